// Round 1
// baseline (1298.269 us; speedup 1.0000x reference)
//
#include <hip/hip_runtime.h>
#include <hip/hip_bf16.h>
#include <math.h>

#define BB 2
#define TT 2048
#define DD 768
#define HH 12
#define ND 64
#define MM (BB*TT)   // 4096

// ---------------------------------------------------------------------------
// Tiled f32 GEMM: out = X[M x D] * W[D x D] (+bias)
// mode 0: write head layout [B,H,T,ND] (+bias)   mode 1: plain [M,D], no bias
// Block: 16x16 threads, 64x64 output tile, BK=16.
// ---------------------------------------------------------------------------
__global__ __launch_bounds__(256) void gemm64(const float* __restrict__ X,
                                              const float* __restrict__ W,
                                              const float* __restrict__ bias,
                                              float* __restrict__ out,
                                              int mode)
{
    __shared__ float As[16][65];   // [k][m], padded
    __shared__ float Bs[16][64];   // [k][n]
    const int tx = threadIdx.x, ty = threadIdx.y;
    const int tid = ty * 16 + tx;
    const int n0 = blockIdx.x * 64;
    const int m0 = blockIdx.y * 64;

    float acc[4][4] = {};

    const int a_r = tid >> 2;          // 0..63
    const int a_c = (tid & 3) * 4;     // 0,4,8,12
    const int b_r = tid >> 4;          // 0..15
    const int b_c = (tid & 15) * 4;    // 0..60

    for (int k0 = 0; k0 < DD; k0 += 16) {
        float4 av = *(const float4*)&X[(size_t)(m0 + a_r) * DD + k0 + a_c];
        As[a_c + 0][a_r] = av.x;
        As[a_c + 1][a_r] = av.y;
        As[a_c + 2][a_r] = av.z;
        As[a_c + 3][a_r] = av.w;
        float4 bv = *(const float4*)&W[(size_t)(k0 + b_r) * DD + n0 + b_c];
        Bs[b_r][b_c + 0] = bv.x;
        Bs[b_r][b_c + 1] = bv.y;
        Bs[b_r][b_c + 2] = bv.z;
        Bs[b_r][b_c + 3] = bv.w;
        __syncthreads();
        #pragma unroll
        for (int kk = 0; kk < 16; ++kk) {
            float a[4], b[4];
            #pragma unroll
            for (int i = 0; i < 4; ++i) a[i] = As[kk][ty + 16 * i];
            #pragma unroll
            for (int j = 0; j < 4; ++j) b[j] = Bs[kk][tx + 16 * j];
            #pragma unroll
            for (int i = 0; i < 4; ++i)
                #pragma unroll
                for (int j = 0; j < 4; ++j)
                    acc[i][j] += a[i] * b[j];
        }
        __syncthreads();
    }

    #pragma unroll
    for (int i = 0; i < 4; ++i) {
        const int m = m0 + ty + 16 * i;
        const int b_idx = m >> 11;      // /2048
        const int t = m & 2047;
        #pragma unroll
        for (int j = 0; j < 4; ++j) {
            const int n = n0 + tx + 16 * j;
            float v = acc[i][j] + (bias ? bias[n] : 0.0f);
            if (mode == 0) {
                const int h = n >> 6, d = n & 63;
                out[(((size_t)(b_idx * HH + h)) * TT + t) * ND + d] = v;
            } else {
                out[(size_t)m * DD + n] = v;
            }
        }
    }
}

// ---------------------------------------------------------------------------
// RoPE applied in-place to Qh, Kh in [B,H,T,ND] layout.
// ---------------------------------------------------------------------------
__global__ void rope_kernel(float* __restrict__ Qh, float* __restrict__ Kh,
                            const float* __restrict__ cosT,
                            const float* __restrict__ sinT)
{
    const int i = blockIdx.x * blockDim.x + threadIdx.x;
    const int total = BB * HH * TT * 32;
    if (i >= total) return;
    const int p  = i & 31;
    const int t  = (i >> 5) & 2047;
    const int bh = i >> 16;            // 32*2048 = 65536
    const float c = cosT[t * 32 + p];
    const float s = sinT[t * 32 + p];
    const size_t base = ((size_t)bh * TT + t) * ND + 2 * p;
    float qr = Qh[base], qi = Qh[base + 1];
    Qh[base]     = qr * c - qi * s;
    Qh[base + 1] = qr * s + qi * c;
    float kr = Kh[base], ki = Kh[base + 1];
    Kh[base]     = kr * c - ki * s;
    Kh[base + 1] = kr * s + ki * c;
}

// ---------------------------------------------------------------------------
// Causal flash attention, f32. Block = (bh, 32 q-rows), 256 threads.
// thread: q = tid/8 (row), dg = tid%8 (owns 8 output dims).
// Writes output directly in [B,T,D] layout for the final projection.
// ---------------------------------------------------------------------------
__global__ __launch_bounds__(256) void attn_kernel(const float* __restrict__ Qh,
                                                   const float* __restrict__ Kh,
                                                   const float* __restrict__ Vh,
                                                   float* __restrict__ Op)
{
    __shared__ float Qs[32][65];
    __shared__ float Ks[32][65];
    __shared__ float Vs[32][65];
    __shared__ float Ps[32][33];
    const int tid = threadIdx.x;
    const int q  = tid >> 3;
    const int dg = tid & 7;
    const int q0 = blockIdx.x * 32;
    const int bh = blockIdx.y;         // b*H + h
    const size_t base = (size_t)bh * TT * ND;

    for (int idx = tid; idx < 32 * 64; idx += 256)
        Qs[idx >> 6][idx & 63] = Qh[base + (size_t)q0 * 64 + idx];

    float O[8] = {};
    float mrow = -1e30f, lrow = 0.0f;
    const float scale = 0.125f;        // 1/sqrt(64)
    __syncthreads();

    for (int k0 = 0; k0 <= q0 + 31; k0 += 32) {
        for (int idx = tid; idx < 32 * 64; idx += 256) {
            const int r = idx >> 6, c = idx & 63;
            Ks[r][c] = Kh[base + (size_t)k0 * 64 + idx];
            Vs[r][c] = Vh[base + (size_t)k0 * 64 + idx];
        }
        __syncthreads();

        // scores: row q, cols kc0..kc0+3
        const int kc0 = dg * 4;
        float s4[4] = {};
        for (int d = 0; d < 64; ++d) {
            const float qv = Qs[q][d];
            #pragma unroll
            for (int j = 0; j < 4; ++j)
                s4[j] += qv * Ks[kc0 + j][d];
        }
        const int qglob = q0 + q;
        float lm = -1e30f;
        #pragma unroll
        for (int j = 0; j < 4; ++j) {
            s4[j] = (k0 + kc0 + j <= qglob) ? s4[j] * scale : -1e30f;
            lm = fmaxf(lm, s4[j]);
        }
        lm = fmaxf(lm, __shfl_xor(lm, 1));
        lm = fmaxf(lm, __shfl_xor(lm, 2));
        lm = fmaxf(lm, __shfl_xor(lm, 4));
        const float newm = fmaxf(mrow, lm);
        float psum = 0.0f;
        #pragma unroll
        for (int j = 0; j < 4; ++j) {
            const float p = __expf(s4[j] - newm);  // underflows to 0 when masked
            Ps[q][kc0 + j] = p;
            psum += p;
        }
        psum += __shfl_xor(psum, 1);
        psum += __shfl_xor(psum, 2);
        psum += __shfl_xor(psum, 4);
        const float alpha = __expf(mrow - newm);
        lrow = lrow * alpha + psum;
        mrow = newm;
        #pragma unroll
        for (int j = 0; j < 8; ++j) O[j] *= alpha;
        __syncthreads();

        for (int kc = 0; kc < 32; ++kc) {
            const float p = Ps[q][kc];
            #pragma unroll
            for (int j = 0; j < 8; ++j)
                O[j] += p * Vs[kc][dg * 8 + j];
        }
        __syncthreads();
    }

    const float inv = 1.0f / lrow;
    const int b_idx = bh / HH, h = bh % HH;
    float* dst = Op + ((size_t)(b_idx * TT + q0 + q)) * DD + h * ND + dg * 8;
    #pragma unroll
    for (int j = 0; j < 8; ++j) dst[j] = O[j] * inv;
}

// ---------------------------------------------------------------------------
extern "C" void kernel_launch(void* const* d_in, const int* in_sizes, int n_in,
                              void* d_out, int out_size, void* d_ws, size_t ws_size,
                              hipStream_t stream)
{
    const float* q  = (const float*)d_in[0];
    const float* k  = (const float*)d_in[1];
    const float* v  = (const float*)d_in[2];
    // d_in[3] = mask (causal tril, implemented analytically)
    const float* wq = (const float*)d_in[4];
    const float* bq = (const float*)d_in[5];
    const float* wk = (const float*)d_in[6];
    const float* bk = (const float*)d_in[7];
    const float* wv = (const float*)d_in[8];
    const float* bv = (const float*)d_in[9];
    const float* wo = (const float*)d_in[10];
    const float* fc = (const float*)d_in[11];
    const float* fs = (const float*)d_in[12];
    float* out = (float*)d_out;

    float* Qh = (float*)d_ws;                    // [B,H,T,ND]
    float* Kh = Qh + (size_t)MM * DD;
    float* Vh = Kh + (size_t)MM * DD;
    float* Op = Vh + (size_t)MM * DD;            // [B,T,D]

    dim3 gblock(16, 16);
    dim3 ggrid(DD / 64, MM / 64);
    gemm64<<<ggrid, gblock, 0, stream>>>(q, wq, bq, Qh, 0);
    gemm64<<<ggrid, gblock, 0, stream>>>(k, wk, bk, Kh, 0);
    gemm64<<<ggrid, gblock, 0, stream>>>(v, wv, bv, Vh, 0);

    const int rope_total = BB * HH * TT * 32;
    rope_kernel<<<(rope_total + 255) / 256, 256, 0, stream>>>(Qh, Kh, fc, fs);

    attn_kernel<<<dim3(TT / 32, BB * HH), 256, 0, stream>>>(Qh, Kh, Vh, Op);

    gemm64<<<ggrid, gblock, 0, stream>>>(Op, wo, nullptr, out, 1);
}

// Round 2
// 168.227 us; speedup vs baseline: 7.7174x; 7.7174x over previous
//
#include <hip/hip_runtime.h>
#include <hip/hip_bf16.h>
#include <math.h>

#define BB 2
#define TT 2048
#define DD 768
#define HH 12
#define ND 64
#define MM (BB*TT)   // 4096

typedef __attribute__((ext_vector_type(8))) short bf16x8;
typedef __attribute__((ext_vector_type(4))) float f32x4;

__device__ __forceinline__ float bf2f(ushort u) {
    union { unsigned int i; float f; } v; v.i = ((unsigned int)u) << 16; return v.f;
}
__device__ __forceinline__ ushort f2bf(float f) {
    union { float f; unsigned int i; } v; v.f = f;
    unsigned int r = v.i + 0x7FFF + ((v.i >> 16) & 1);   // RNE
    return (ushort)(r >> 16);
}

// async global->LDS, 16B per lane. LDS base must be wave-uniform; HW adds lane*16.
__device__ __forceinline__ void cp16(void* lds, const void* g) {
    __builtin_amdgcn_global_load_lds(
        (const __attribute__((address_space(1))) void*)g,
        (__attribute__((address_space(3))) void*)lds, 16, 0, 0);
}

// ---------------------------------------------------------------------------
// f32 -> bf16 conversion for q,k,v (layout preserved)
// ---------------------------------------------------------------------------
__global__ void conv_x3(const float* __restrict__ x0, const float* __restrict__ x1,
                        const float* __restrict__ x2,
                        ushort* __restrict__ o0, ushort* __restrict__ o1,
                        ushort* __restrict__ o2)
{
    const float* x = blockIdx.z == 0 ? x0 : (blockIdx.z == 1 ? x1 : x2);
    ushort* o = blockIdx.z == 0 ? o0 : (blockIdx.z == 1 ? o1 : o2);
    int i = (blockIdx.x * 256 + threadIdx.x) * 4;
    if (i >= MM * DD) return;
    float4 v = *(const float4*)&x[i];
    ushort4 r;
    r.x = f2bf(v.x); r.y = f2bf(v.y); r.z = f2bf(v.z); r.w = f2bf(v.w);
    *(ushort4*)&o[i] = r;
}

// ---------------------------------------------------------------------------
// weights f32 [k][n] -> bf16 transposed [n][k]
// ---------------------------------------------------------------------------
__global__ __launch_bounds__(256) void conv_wT(const float* __restrict__ w0, const float* __restrict__ w1,
                        const float* __restrict__ w2, const float* __restrict__ w3,
                        ushort* __restrict__ o0, ushort* __restrict__ o1,
                        ushort* __restrict__ o2, ushort* __restrict__ o3)
{
    __shared__ ushort tile[64][72];
    const float* w = blockIdx.z == 0 ? w0 : blockIdx.z == 1 ? w1 : blockIdx.z == 2 ? w2 : w3;
    ushort* o = blockIdx.z == 0 ? o0 : blockIdx.z == 1 ? o1 : blockIdx.z == 2 ? o2 : o3;
    const int k0 = blockIdx.y * 64, n0 = blockIdx.x * 64;
    #pragma unroll
    for (int it = 0; it < 4; ++it) {
        int e = (threadIdx.x + it * 256) * 4;
        int r = e >> 6, c = e & 63;
        float4 v = *(const float4*)&w[(size_t)(k0 + r) * DD + n0 + c];
        tile[c + 0][r] = f2bf(v.x);
        tile[c + 1][r] = f2bf(v.y);
        tile[c + 2][r] = f2bf(v.z);
        tile[c + 3][r] = f2bf(v.w);
    }
    __syncthreads();
    #pragma unroll
    for (int it = 0; it < 4; ++it) {
        int e = (threadIdx.x + it * 256) * 4;
        int nr = e >> 6, kc = e & 63;
        ushort4 r4;
        r4.x = tile[nr][kc + 0];
        r4.y = tile[nr][kc + 1];
        r4.z = tile[nr][kc + 2];
        r4.w = tile[nr][kc + 3];
        *(ushort4*)&o[(size_t)(n0 + nr) * DD + k0 + kc] = r4;
    }
}

// ---------------------------------------------------------------------------
// MFMA GEMM: A[M=4096][K=768] bf16 x WT[N][K] bf16.
// MODE 0: out bf16 head layout [B,H,T,ND] + f32 bias (QKV, fused via z)
// MODE 1: out f32 flat [M][N], no bias (final projection)
// 128x128 tile, BK=32, 4 waves of 64x64, 2-phase prefetch.
// ---------------------------------------------------------------------------
struct GArgs { const ushort* x; const ushort* wt; const float* bias; void* out; };

template<int MODE>
__global__ __launch_bounds__(256) void gemm_bf16(GArgs a0, GArgs a1, GArgs a2)
{
    __shared__ __align__(16) ushort As[2][128 * 32];
    __shared__ __align__(16) ushort Bs[2][128 * 32];
    GArgs ga = (blockIdx.z == 0) ? a0 : (blockIdx.z == 1 ? a1 : a2);
    const int tid = threadIdx.x;
    const int w = tid >> 6, l = tid & 63;
    const int wr = w >> 1, wc = w & 1;
    const int n0 = blockIdx.x * 128, m0 = blockIdx.y * 128;

    f32x4 acc[4][4] = {};

    auto stage = [&](int buf, int k0) {
        #pragma unroll
        for (int it = 0; it < 2; ++it) {
            int o = it * 4096 + w * 1024 + l * 16;
            int row = o >> 6, kb = o & 63;
            cp16((char*)&As[buf][0] + it * 4096 + w * 1024,
                 (const char*)ga.x + (size_t)(m0 + row) * (DD * 2) + k0 * 2 + kb);
            cp16((char*)&Bs[buf][0] + it * 4096 + w * 1024,
                 (const char*)ga.wt + (size_t)(n0 + row) * (DD * 2) + k0 * 2 + kb);
        }
    };
    stage(0, 0);
    __syncthreads();
    const int NK = DD / 32;
    for (int t = 0; t < NK; ++t) {
        const int cur = t & 1;
        if (t + 1 < NK) stage(cur ^ 1, (t + 1) * 32);
        const char* ab = (const char*)&As[cur][0];
        const char* bb = (const char*)&Bs[cur][0];
        bf16x8 af[4], bfr[4];
        #pragma unroll
        for (int i = 0; i < 4; ++i)
            af[i] = *(const bf16x8*)(ab + (64 * wr + 16 * i + (l & 15)) * 64 + (l >> 4) * 16);
        #pragma unroll
        for (int j = 0; j < 4; ++j)
            bfr[j] = *(const bf16x8*)(bb + (64 * wc + 16 * j + (l & 15)) * 64 + (l >> 4) * 16);
        #pragma unroll
        for (int i = 0; i < 4; ++i)
            #pragma unroll
            for (int j = 0; j < 4; ++j)
                acc[i][j] = __builtin_amdgcn_mfma_f32_16x16x32_bf16(af[i], bfr[j], acc[i][j], 0, 0, 0);
        __syncthreads();
    }
    #pragma unroll
    for (int i = 0; i < 4; ++i) {
        #pragma unroll
        for (int j = 0; j < 4; ++j) {
            #pragma unroll
            for (int r = 0; r < 4; ++r) {
                const int m = m0 + 64 * wr + 16 * i + (l >> 4) * 4 + r;
                const int n = n0 + 64 * wc + 16 * j + (l & 15);
                float v = acc[i][j][r];
                if (MODE == 0) {
                    v += ga.bias[n];
                    const int b = m >> 11, tt = m & 2047;
                    const int h = n >> 6, d = n & 63;
                    ((ushort*)ga.out)[((size_t)(b * HH + h) * TT + tt) * ND + d] = f2bf(v);
                } else {
                    ((float*)ga.out)[(size_t)m * DD + n] = v;
                }
            }
        }
    }
}

// ---------------------------------------------------------------------------
// RoPE in place on bf16 head-layout Q,K
// ---------------------------------------------------------------------------
__global__ void rope_bf16(ushort* __restrict__ Qh, ushort* __restrict__ Kh,
                          const float* __restrict__ cT, const float* __restrict__ sT)
{
    int i = blockIdx.x * 256 + threadIdx.x;
    if (i >= BB * HH * TT * 32) return;
    const int p = i & 31, t = (i >> 5) & 2047, bh = i >> 16;
    const float c = cT[t * 32 + p], s = sT[t * 32 + p];
    const size_t base = ((size_t)bh * TT + t) * ND + 2 * p;
    ushort2 q = *(ushort2*)&Qh[base];
    float qr = bf2f(q.x), qi = bf2f(q.y);
    ushort2 qo; qo.x = f2bf(qr * c - qi * s); qo.y = f2bf(qr * s + qi * c);
    *(ushort2*)&Qh[base] = qo;
    ushort2 k = *(ushort2*)&Kh[base];
    float kr = bf2f(k.x), ki = bf2f(k.y);
    ushort2 ko; ko.x = f2bf(kr * c - ki * s); ko.y = f2bf(kr * s + ki * c);
    *(ushort2*)&Kh[base] = ko;
}

// ---------------------------------------------------------------------------
// Vh [bh][t][d] -> VhT [bh][d][t]
// ---------------------------------------------------------------------------
__global__ __launch_bounds__(256) void transpose_v(const ushort* __restrict__ Vh,
                                                   ushort* __restrict__ VhT)
{
    __shared__ ushort tile[64][72];
    const int t0 = blockIdx.x * 64, bh = blockIdx.y;
    const ushort* src = Vh + ((size_t)bh * TT + t0) * ND;
    #pragma unroll
    for (int it = 0; it < 4; ++it) {
        int e = (threadIdx.x + it * 256) * 4;
        int r = e >> 6, c = e & 63;
        ushort4 v = *(const ushort4*)&src[r * ND + c];
        tile[r][c + 0] = v.x; tile[r][c + 1] = v.y;
        tile[r][c + 2] = v.z; tile[r][c + 3] = v.w;
    }
    __syncthreads();
    #pragma unroll
    for (int it = 0; it < 4; ++it) {
        int e = (threadIdx.x + it * 256) * 4;
        int d = e >> 6, tc = e & 63;
        ushort4 r4;
        r4.x = tile[tc + 0][d]; r4.y = tile[tc + 1][d];
        r4.z = tile[tc + 2][d]; r4.w = tile[tc + 3][d];
        *(ushort4*)&VhT[((size_t)bh * ND + d) * TT + t0 + tc] = r4;
    }
}

// ---------------------------------------------------------------------------
// MFMA flash attention. Block = (q-tile of 64, bh). 4 waves, 16 q-rows each.
// KVBLK=64, double-buffered LDS, XOR-swizzled rows (byte ^= (row&7)<<4).
// ---------------------------------------------------------------------------
__global__ __launch_bounds__(256) void attn_mfma(const ushort* __restrict__ Qh,
                                                 const ushort* __restrict__ Kh,
                                                 const ushort* __restrict__ VhT,
                                                 ushort* __restrict__ Op)
{
    __shared__ __align__(16) ushort Qs[4096];       // [64 q][64 d] swizzled
    __shared__ __align__(16) ushort Ks[2][4096];    // [64 kv][64 d] swizzled
    __shared__ __align__(16) ushort Vs[2][4096];    // [64 d][64 kv] swizzled
    __shared__ __align__(16) ushort Ps[4][1024];    // per-wave [16 q][64 kv] swizzled
    const int tid = threadIdx.x;
    const int w = tid >> 6, l = tid & 63;
    const int qblk = gridDim.x - 1 - blockIdx.x;    // longest blocks first
    const int q0 = qblk * 64;
    const int bh = blockIdx.y;
    const ushort* Qg = Qh + ((size_t)bh * TT + q0) * ND;
    const ushort* Kg = Kh + (size_t)bh * TT * ND;
    const ushort* Vg = VhT + (size_t)bh * ND * TT;

    // stage Q (pre-swizzled source)
    #pragma unroll
    for (int it = 0; it < 2; ++it) {
        int o = it * 4096 + w * 1024 + l * 16;
        int row = o >> 7, inner = o & 127;
        cp16((char*)Qs + it * 4096 + w * 1024,
             (const char*)Qg + row * (ND * 2) + (inner ^ ((row & 7) << 4)));
    }
    auto stageKV = [&](int buf, int kv0) {
        #pragma unroll
        for (int it = 0; it < 2; ++it) {
            int o = it * 4096 + w * 1024 + l * 16;
            int row = o >> 7, inner = o & 127;
            int swz = inner ^ ((row & 7) << 4);
            cp16((char*)&Ks[buf][0] + it * 4096 + w * 1024,
                 (const char*)Kg + (size_t)(kv0 + row) * (ND * 2) + swz);
            cp16((char*)&Vs[buf][0] + it * 4096 + w * 1024,
                 (const char*)Vg + (size_t)row * (TT * 2) + kv0 * 2 + swz);
        }
    };
    stageKV(0, 0);
    __syncthreads();

    const int col0 = l & 15, rg = l >> 4;
    // Q fragments (constant over the KV loop)
    const int qrow = 16 * w + col0;
    bf16x8 qf[2];
    #pragma unroll
    for (int ks = 0; ks < 2; ++ks)
        qf[ks] = *(const bf16x8*)((const char*)Qs + qrow * 128 +
                                  ((ks * 64 + rg * 16) ^ ((qrow & 7) << 4)));

    const int qbase = q0 + 16 * w + rg * 4;     // + r = global q row
    float mrow[4] = {-1e30f, -1e30f, -1e30f, -1e30f};
    float lrow[4] = {0.f, 0.f, 0.f, 0.f};
    f32x4 of[4] = {};

    const int nt = qblk + 1;
    for (int t = 0; t < nt; ++t) {
        const int cur = t & 1;
        if (t + 1 < nt) stageKV(cur ^ 1, (t + 1) * 64);
        const int kv0 = t * 64;
        const char* kb = (const char*)&Ks[cur][0];
        const char* vb = (const char*)&Vs[cur][0];

        // S = Q K^T
        f32x4 sf[4];
        #pragma unroll
        for (int cf = 0; cf < 4; ++cf) {
            f32x4 s = {};
            #pragma unroll
            for (int ks = 0; ks < 2; ++ks) {
                const int krow = 16 * cf + col0;
                bf16x8 kf = *(const bf16x8*)(kb + krow * 128 +
                                             ((ks * 64 + rg * 16) ^ ((krow & 7) << 4)));
                s = __builtin_amdgcn_mfma_f32_16x16x32_bf16(qf[ks], kf, s, 0, 0, 0);
            }
            sf[cf] = s;
        }
        // scale + causal mask + row max
        float tm[4] = {-1e30f, -1e30f, -1e30f, -1e30f};
        #pragma unroll
        for (int cf = 0; cf < 4; ++cf) {
            const int kcol = kv0 + 16 * cf + col0;
            #pragma unroll
            for (int r = 0; r < 4; ++r) {
                float sv = sf[cf][r] * 0.125f;
                if (kcol > qbase + r) sv = -1e30f;
                sf[cf][r] = sv;
                tm[r] = fmaxf(tm[r], sv);
            }
        }
        #pragma unroll
        for (int d = 1; d < 16; d <<= 1) {
            #pragma unroll
            for (int r = 0; r < 4; ++r) tm[r] = fmaxf(tm[r], __shfl_xor(tm[r], d));
        }
        float al[4], rs[4] = {0.f, 0.f, 0.f, 0.f};
        #pragma unroll
        for (int r = 0; r < 4; ++r) {
            const float nm = fmaxf(mrow[r], tm[r]);
            al[r] = __expf(mrow[r] - nm);
            mrow[r] = nm;
        }
        // P = exp(S - m), store bf16 to per-wave LDS (swizzled)
        #pragma unroll
        for (int cf = 0; cf < 4; ++cf) {
            #pragma unroll
            for (int r = 0; r < 4; ++r) {
                const float p = __expf(sf[cf][r] - mrow[r]);
                rs[r] += p;
                const int prow = rg * 4 + r;
                const int pbyte = prow * 128 + (((16 * cf + col0) * 2) ^ ((prow & 7) << 4));
                *(ushort*)((char*)&Ps[w][0] + pbyte) = f2bf(p);
            }
        }
        #pragma unroll
        for (int d = 1; d < 16; d <<= 1) {
            #pragma unroll
            for (int r = 0; r < 4; ++r) rs[r] += __shfl_xor(rs[r], d);
        }
        #pragma unroll
        for (int r = 0; r < 4; ++r) lrow[r] = lrow[r] * al[r] + rs[r];
        #pragma unroll
        for (int df = 0; df < 4; ++df) {
            #pragma unroll
            for (int r = 0; r < 4; ++r) of[df][r] *= al[r];
        }
        // PV
        bf16x8 pf[2];
        #pragma unroll
        for (int ks = 0; ks < 2; ++ks)
            pf[ks] = *(const bf16x8*)((const char*)&Ps[w][0] + col0 * 128 +
                                      ((ks * 64 + rg * 16) ^ ((col0 & 7) << 4)));
        #pragma unroll
        for (int df = 0; df < 4; ++df) {
            #pragma unroll
            for (int ks = 0; ks < 2; ++ks) {
                const int vrow = 16 * df + col0;
                bf16x8 vf = *(const bf16x8*)(vb + vrow * 128 +
                                             ((ks * 64 + rg * 16) ^ ((vrow & 7) << 4)));
                of[df] = __builtin_amdgcn_mfma_f32_16x16x32_bf16(pf[ks], vf, of[df], 0, 0, 0);
            }
        }
        __syncthreads();
    }

    // epilogue: Op [b][t][h*64+d] bf16
    const int b = bh / HH, h = bh % HH;
    #pragma unroll
    for (int r = 0; r < 4; ++r) {
        const float inv = 1.0f / lrow[r];
        const int trow = qbase + r;
        const size_t base = ((size_t)(b * TT + trow)) * DD + h * ND;
        #pragma unroll
        for (int df = 0; df < 4; ++df)
            Op[base + 16 * df + col0] = f2bf(of[df][r] * inv);
    }
}

// ---------------------------------------------------------------------------
extern "C" void kernel_launch(void* const* d_in, const int* in_sizes, int n_in,
                              void* d_out, int out_size, void* d_ws, size_t ws_size,
                              hipStream_t stream)
{
    const float* q  = (const float*)d_in[0];
    const float* k  = (const float*)d_in[1];
    const float* v  = (const float*)d_in[2];
    const float* wq = (const float*)d_in[4];
    const float* bq = (const float*)d_in[5];
    const float* wk = (const float*)d_in[6];
    const float* bk = (const float*)d_in[7];
    const float* wv = (const float*)d_in[8];
    const float* bv = (const float*)d_in[9];
    const float* wo = (const float*)d_in[10];
    const float* fc = (const float*)d_in[11];
    const float* fs = (const float*)d_in[12];
    float* out = (float*)d_out;

    ushort* qB  = (ushort*)d_ws;           // [M][D] bf16
    ushort* kB  = qB  + (size_t)MM * DD;
    ushort* vB  = kB  + (size_t)MM * DD;
    ushort* wqT = vB  + (size_t)MM * DD;   // [n][k] bf16
    ushort* wkT = wqT + (size_t)DD * DD;
    ushort* wvT = wkT + (size_t)DD * DD;
    ushort* woT = wvT + (size_t)DD * DD;
    ushort* Qh  = woT + (size_t)DD * DD;   // [B,H,T,ND] bf16
    ushort* Kh  = Qh  + (size_t)MM * DD;
    ushort* Vh  = Kh  + (size_t)MM * DD;
    ushort* VhT = kB;                      // alias: kB dead after QKV GEMM
    ushort* Op  = qB;                      // alias: qB dead after QKV GEMM

    conv_x3<<<dim3(MM * DD / 4 / 256, 1, 3), 256, 0, stream>>>(q, k, v, qB, kB, vB);
    conv_wT<<<dim3(DD / 64, DD / 64, 4), 256, 0, stream>>>(wq, wk, wv, wo, wqT, wkT, wvT, woT);

    GArgs aq{qB, wqT, bq, (void*)Qh};
    GArgs ak{kB, wkT, bk, (void*)Kh};
    GArgs av{vB, wvT, bv, (void*)Vh};
    gemm_bf16<0><<<dim3(DD / 128, MM / 128, 3), 256, 0, stream>>>(aq, ak, av);

    rope_bf16<<<dim3(BB * HH * TT * 32 / 256), 256, 0, stream>>>(Qh, Kh, fc, fs);
    transpose_v<<<dim3(TT / 64, BB * HH), 256, 0, stream>>>(Vh, VhT);

    attn_mfma<<<dim3(TT / 64, BB * HH), 256, 0, stream>>>(Qh, Kh, VhT, Op);

    GArgs ao{Op, woT, nullptr, (void*)out};
    gemm_bf16<1><<<dim3(DD / 128, MM / 128, 1), 256, 0, stream>>>(ao, ao, ao);
}

// Round 3
// 150.722 us; speedup vs baseline: 8.6137x; 1.1161x over previous
//
#include <hip/hip_runtime.h>
#include <hip/hip_bf16.h>
#include <math.h>

#define BB 2
#define TT 2048
#define DD 768
#define HH 12
#define ND 64
#define MM (BB*TT)   // 4096

typedef __attribute__((ext_vector_type(8))) short bf16x8;
typedef __attribute__((ext_vector_type(4))) float f32x4;
typedef __attribute__((ext_vector_type(16))) float f32x16;

__device__ __forceinline__ float bf2f(ushort u) {
    union { unsigned int i; float f; } v; v.i = ((unsigned int)u) << 16; return v.f;
}
__device__ __forceinline__ ushort f2bf(float f) {
    union { float f; unsigned int i; } v; v.f = f;
    unsigned int r = v.i + 0x7FFF + ((v.i >> 16) & 1);   // RNE
    return (ushort)(r >> 16);
}

// async global->LDS, 16B per lane. LDS base must be wave-uniform; HW adds lane*16.
__device__ __forceinline__ void cp16(void* lds, const void* g) {
    __builtin_amdgcn_global_load_lds(
        (const __attribute__((address_space(1))) void*)g,
        (__attribute__((address_space(3))) void*)lds, 16, 0, 0);
}

// 2^x via raw v_exp_f32 (single TRANS instruction)
__device__ __forceinline__ float fexp2(float x) {
    float r; asm("v_exp_f32 %0, %1" : "=v"(r) : "v"(x)); return r;
}
// pack two f32 -> 2x bf16 in one dword (lo = a, hi = b)
__device__ __forceinline__ unsigned int pk_bf16(float a, float b) {
    unsigned int r; asm("v_cvt_pk_bf16_f32 %0, %1, %2" : "=v"(r) : "v"(a), "v"(b)); return r;
}

// swap upper 32 lanes of a with lower 32 lanes of b
__device__ __forceinline__ void plswap(unsigned int& a, unsigned int& b) {
#if __has_builtin(__builtin_amdgcn_permlane32_swap)
    auto r = __builtin_amdgcn_permlane32_swap(a, b, false, false);
    a = r[0]; b = r[1];
#else
    unsigned int sa = __shfl_xor((int)a, 32), sb = __shfl_xor((int)b, 32);
    bool hi = (threadIdx.x & 63) >= 32;
    unsigned int na = hi ? sb : a, nb = hi ? b : sa;
    a = na; b = nb;
#endif
}
// value of x at lane^32 (both lanes get partner's value)
__device__ __forceinline__ float partner32(float x, int hi) {
#if __has_builtin(__builtin_amdgcn_permlane32_swap)
    unsigned int u = __float_as_uint(x);
    auto r = __builtin_amdgcn_permlane32_swap(u, u, false, false);
    return __uint_as_float(hi ? r[0] : r[1]);
#else
    return __shfl_xor(x, 32);
#endif
}

// ---------------------------------------------------------------------------
// f32 -> bf16 conversion for q,k,v (layout preserved)
// ---------------------------------------------------------------------------
__global__ void conv_x3(const float* __restrict__ x0, const float* __restrict__ x1,
                        const float* __restrict__ x2,
                        ushort* __restrict__ o0, ushort* __restrict__ o1,
                        ushort* __restrict__ o2)
{
    const float* x = blockIdx.z == 0 ? x0 : (blockIdx.z == 1 ? x1 : x2);
    ushort* o = blockIdx.z == 0 ? o0 : (blockIdx.z == 1 ? o1 : o2);
    int i = (blockIdx.x * 256 + threadIdx.x) * 4;
    if (i >= MM * DD) return;
    float4 v = *(const float4*)&x[i];
    ushort4 r;
    r.x = f2bf(v.x); r.y = f2bf(v.y); r.z = f2bf(v.z); r.w = f2bf(v.w);
    *(ushort4*)&o[i] = r;
}

// ---------------------------------------------------------------------------
// weights f32 [k][n] -> bf16 transposed [n][k]
// ---------------------------------------------------------------------------
__global__ __launch_bounds__(256) void conv_wT(const float* __restrict__ w0, const float* __restrict__ w1,
                        const float* __restrict__ w2, const float* __restrict__ w3,
                        ushort* __restrict__ o0, ushort* __restrict__ o1,
                        ushort* __restrict__ o2, ushort* __restrict__ o3)
{
    __shared__ ushort tile[64][72];
    const float* w = blockIdx.z == 0 ? w0 : blockIdx.z == 1 ? w1 : blockIdx.z == 2 ? w2 : w3;
    ushort* o = blockIdx.z == 0 ? o0 : blockIdx.z == 1 ? o1 : blockIdx.z == 2 ? o2 : o3;
    const int k0 = blockIdx.y * 64, n0 = blockIdx.x * 64;
    #pragma unroll
    for (int it = 0; it < 4; ++it) {
        int e = (threadIdx.x + it * 256) * 4;
        int r = e >> 6, c = e & 63;
        float4 v = *(const float4*)&w[(size_t)(k0 + r) * DD + n0 + c];
        tile[c + 0][r] = f2bf(v.x);
        tile[c + 1][r] = f2bf(v.y);
        tile[c + 2][r] = f2bf(v.z);
        tile[c + 3][r] = f2bf(v.w);
    }
    __syncthreads();
    #pragma unroll
    for (int it = 0; it < 4; ++it) {
        int e = (threadIdx.x + it * 256) * 4;
        int nr = e >> 6, kc = e & 63;
        ushort4 r4;
        r4.x = tile[nr][kc + 0];
        r4.y = tile[nr][kc + 1];
        r4.z = tile[nr][kc + 2];
        r4.w = tile[nr][kc + 3];
        *(ushort4*)&o[(size_t)(n0 + nr) * DD + k0 + kc] = r4;
    }
}

// ---------------------------------------------------------------------------
// MFMA GEMM: A[M=4096][K=768] bf16 x WT[N][K] bf16.
// MODE 0: out bf16 head layout [B,H,T,ND] + f32 bias (QKV, fused via z)
// MODE 1: out f32 flat [M][N], no bias (final projection)
// 128x128 tile, BK=32, 4 waves of 64x64, 2-phase prefetch.
// ---------------------------------------------------------------------------
struct GArgs { const ushort* x; const ushort* wt; const float* bias; void* out; };

template<int MODE>
__global__ __launch_bounds__(256) void gemm_bf16(GArgs a0, GArgs a1, GArgs a2)
{
    __shared__ __align__(16) ushort As[2][128 * 32];
    __shared__ __align__(16) ushort Bs[2][128 * 32];
    GArgs ga = (blockIdx.z == 0) ? a0 : (blockIdx.z == 1 ? a1 : a2);
    const int tid = threadIdx.x;
    const int w = tid >> 6, l = tid & 63;
    const int wr = w >> 1, wc = w & 1;
    const int n0 = blockIdx.x * 128, m0 = blockIdx.y * 128;

    f32x4 acc[4][4] = {};

    auto stage = [&](int buf, int k0) {
        #pragma unroll
        for (int it = 0; it < 2; ++it) {
            int o = it * 4096 + w * 1024 + l * 16;
            int row = o >> 6, kb = o & 63;
            cp16((char*)&As[buf][0] + it * 4096 + w * 1024,
                 (const char*)ga.x + (size_t)(m0 + row) * (DD * 2) + k0 * 2 + kb);
            cp16((char*)&Bs[buf][0] + it * 4096 + w * 1024,
                 (const char*)ga.wt + (size_t)(n0 + row) * (DD * 2) + k0 * 2 + kb);
        }
    };
    stage(0, 0);
    __syncthreads();
    const int NK = DD / 32;
    for (int t = 0; t < NK; ++t) {
        const int cur = t & 1;
        if (t + 1 < NK) stage(cur ^ 1, (t + 1) * 32);
        const char* ab = (const char*)&As[cur][0];
        const char* bb = (const char*)&Bs[cur][0];
        bf16x8 af[4], bfr[4];
        #pragma unroll
        for (int i = 0; i < 4; ++i)
            af[i] = *(const bf16x8*)(ab + (64 * wr + 16 * i + (l & 15)) * 64 + (l >> 4) * 16);
        #pragma unroll
        for (int j = 0; j < 4; ++j)
            bfr[j] = *(const bf16x8*)(bb + (64 * wc + 16 * j + (l & 15)) * 64 + (l >> 4) * 16);
        #pragma unroll
        for (int i = 0; i < 4; ++i)
            #pragma unroll
            for (int j = 0; j < 4; ++j)
                acc[i][j] = __builtin_amdgcn_mfma_f32_16x16x32_bf16(af[i], bfr[j], acc[i][j], 0, 0, 0);
        __syncthreads();
    }
    #pragma unroll
    for (int i = 0; i < 4; ++i) {
        #pragma unroll
        for (int j = 0; j < 4; ++j) {
            #pragma unroll
            for (int r = 0; r < 4; ++r) {
                const int m = m0 + 64 * wr + 16 * i + (l >> 4) * 4 + r;
                const int n = n0 + 64 * wc + 16 * j + (l & 15);
                float v = acc[i][j][r];
                if (MODE == 0) {
                    v += ga.bias[n];
                    const int b = m >> 11, tt = m & 2047;
                    const int h = n >> 6, d = n & 63;
                    ((ushort*)ga.out)[((size_t)(b * HH + h) * TT + tt) * ND + d] = f2bf(v);
                } else {
                    ((float*)ga.out)[(size_t)m * DD + n] = v;
                }
            }
        }
    }
}

// ---------------------------------------------------------------------------
// RoPE in place on bf16 head-layout Q,K.
// Q additionally pre-scaled by 0.125*log2(e) so attention scores are in
// exp2 domain (softmax uses raw v_exp_f32).
// ---------------------------------------------------------------------------
#define QSCALE 0.18033688011112043f   // 0.125 * log2(e)
__global__ void rope_bf16(ushort* __restrict__ Qh, ushort* __restrict__ Kh,
                          const float* __restrict__ cT, const float* __restrict__ sT)
{
    int i = blockIdx.x * 256 + threadIdx.x;
    if (i >= BB * HH * TT * 32) return;
    const int p = i & 31, t = (i >> 5) & 2047, bh = i >> 16;
    const float c = cT[t * 32 + p], s = sT[t * 32 + p];
    const size_t base = ((size_t)bh * TT + t) * ND + 2 * p;
    ushort2 q = *(ushort2*)&Qh[base];
    float qr = bf2f(q.x), qi = bf2f(q.y);
    ushort2 qo; qo.x = f2bf((qr * c - qi * s) * QSCALE); qo.y = f2bf((qr * s + qi * c) * QSCALE);
    *(ushort2*)&Qh[base] = qo;
    ushort2 k = *(ushort2*)&Kh[base];
    float kr = bf2f(k.x), ki = bf2f(k.y);
    ushort2 ko; ko.x = f2bf(kr * c - ki * s); ko.y = f2bf(kr * s + ki * c);
    *(ushort2*)&Kh[base] = ko;
}

// ---------------------------------------------------------------------------
// Vh [bh][t][d] -> VhT [bh][d][t]
// ---------------------------------------------------------------------------
__global__ __launch_bounds__(256) void transpose_v(const ushort* __restrict__ Vh,
                                                   ushort* __restrict__ VhT)
{
    __shared__ ushort tile[64][72];
    const int t0 = blockIdx.x * 64, bh = blockIdx.y;
    const ushort* src = Vh + ((size_t)bh * TT + t0) * ND;
    #pragma unroll
    for (int it = 0; it < 4; ++it) {
        int e = (threadIdx.x + it * 256) * 4;
        int r = e >> 6, c = e & 63;
        ushort4 v = *(const ushort4*)&src[r * ND + c];
        tile[r][c + 0] = v.x; tile[r][c + 1] = v.y;
        tile[r][c + 2] = v.z; tile[r][c + 3] = v.w;
    }
    __syncthreads();
    #pragma unroll
    for (int it = 0; it < 4; ++it) {
        int e = (threadIdx.x + it * 256) * 4;
        int d = e >> 6, tc = e & 63;
        ushort4 r4;
        r4.x = tile[tc + 0][d]; r4.y = tile[tc + 1][d];
        r4.z = tile[tc + 2][d]; r4.w = tile[tc + 3][d];
        *(ushort4*)&VhT[((size_t)bh * ND + d) * TT + t0 + tc] = r4;
    }
}

// ---------------------------------------------------------------------------
// MFMA flash attention, 32x32 swapped-operand structure (guide §B).
// Block = 4 waves x 32 q-rows = 128 q rows. KVBLK=64, double-buffered
// swizzled LDS for K and V^T. S^T = mfma(K, Q): lane owns q-col (l&31),
// 32 k-values in regs -> lane-local softmax (permlane32_swap for partner).
// P packed in-register (cvt_pk + permlane32_swap) into PV's B-fragment.
// O^T = mfma(V^T, P): accumulator stays per-lane-q.
// ---------------------------------------------------------------------------
__global__ __launch_bounds__(256) void attn_mfma2(const ushort* __restrict__ Qh,
                                                  const ushort* __restrict__ Kh,
                                                  const ushort* __restrict__ VhT,
                                                  ushort* __restrict__ Op)
{
    __shared__ __align__(16) ushort Ks[2][4096];    // [64 kv][64 d] swizzled
    __shared__ __align__(16) ushort Vs[2][4096];    // [64 d][64 kv] swizzled
    const int tid = threadIdx.x;
    const int w = tid >> 6, l = tid & 63;
    const int lq = l & 31, hi = l >> 5;
    const int qblk = gridDim.x - 1 - blockIdx.x;    // longest blocks first
    const int q0 = qblk * 128;
    const int bh = blockIdx.y;
    const int q0w = q0 + w * 32;
    const int qg = q0w + lq;                        // this lane's q row

    const ushort* Qg = Qh + ((size_t)bh * TT + q0w) * ND;
    const ushort* Kg = Kh + (size_t)bh * TT * ND;
    const ushort* Vg = VhT + (size_t)bh * ND * TT;

    // Q fragments from global (B-operand: lane holds q row lq, d = ks*16+hi*8+e)
    bf16x8 qf[4];
    #pragma unroll
    for (int ks = 0; ks < 4; ++ks)
        qf[ks] = *(const bf16x8*)((const char*)Qg + lq * 128 + ks * 32 + hi * 16);

    auto stageKV = [&](int buf, int kv0) {
        #pragma unroll
        for (int it = 0; it < 2; ++it) {
            int o = it * 4096 + w * 1024 + l * 16;
            int row = o >> 7, inner = o & 127;
            int swz = inner ^ ((row & 7) << 4);
            cp16((char*)&Ks[buf][0] + it * 4096 + w * 1024,
                 (const char*)Kg + (size_t)(kv0 + row) * 128 + swz);
            cp16((char*)&Vs[buf][0] + it * 4096 + w * 1024,
                 (const char*)Vg + (size_t)row * (TT * 2) + kv0 * 2 + swz);
        }
    };

    float m = -1e30f, lsum = 0.f;
    f32x16 o0 = {}, o1 = {};

    const int nt = 2 * qblk + 2;
    stageKV(0, 0);
    __syncthreads();
    for (int t = 0; t < nt; ++t) {
        const int cur = t & 1;
        if (t + 1 < nt) stageKV(cur ^ 1, (t + 1) * 64);
        const char* kb = (const char*)&Ks[cur][0];
        const char* vb = (const char*)&Vs[cur][0];
        #pragma unroll
        for (int s = 0; s < 2; ++s) {
            const int kv0s = t * 64 + s * 32;
            if (kv0s > q0w + 31) continue;          // fully masked (wave-uniform)

            // S^T[kv][q] over this 32-kv subtile
            f32x16 st = {};
            #pragma unroll
            for (int ks = 0; ks < 4; ++ks) {
                bf16x8 kf = *(const bf16x8*)(kb + (s * 32 + lq) * 128 +
                                             ((ks * 32 + hi * 16) ^ ((lq & 7) << 4)));
                st = __builtin_amdgcn_mfma_f32_32x32x16_bf16(kf, qf[ks], st, 0, 0, 0);
            }

            // causal mask + tile max (S already in log2 domain via Q pre-scale)
            float tm = -1e30f;
            if (kv0s + 31 > q0w) {
                #pragma unroll
                for (int r = 0; r < 16; ++r) {
                    const int kvg = kv0s + (r & 3) + 8 * (r >> 2) + 4 * hi;
                    float x = (kvg <= qg) ? st[r] : -1e30f;
                    st[r] = x;
                    tm = fmaxf(tm, x);
                }
            } else {
                #pragma unroll
                for (int r = 0; r < 16; ++r) tm = fmaxf(tm, st[r]);
            }
            tm = fmaxf(tm, partner32(tm, hi));

            // defer-max (T13): skip rescale if max growth <= 8 nats (11.5 log2)
            const bool defer = __all(tm <= m + 11.5f);
            float alpha = 1.f;
            if (!defer) {
                const float nm = fmaxf(m, tm);
                alpha = fexp2(m - nm);
                m = nm;
            }

            // P = exp2(S - m), rowsum, pack to bf16 pairs
            float rs = 0.f;
            unsigned int pk8[8];
            #pragma unroll
            for (int i = 0; i < 8; ++i) {
                const float p0 = fexp2(st[2 * i + 0] - m);
                const float p1 = fexp2(st[2 * i + 1] - m);
                rs += p0 + p1;
                pk8[i] = pk_bf16(p0, p1);
            }
            rs += partner32(rs, hi);
            lsum = lsum * alpha + rs;

            // rearrange into PV B-fragments: lane q, kv = slice*16 + hi*8 + e
            plswap(pk8[0], pk8[2]);
            plswap(pk8[1], pk8[3]);
            plswap(pk8[4], pk8[6]);
            plswap(pk8[5], pk8[7]);
            union { unsigned int u[4]; bf16x8 v; } pa0, pa1;
            pa0.u[0] = pk8[0]; pa0.u[1] = pk8[1]; pa0.u[2] = pk8[2]; pa0.u[3] = pk8[3];
            pa1.u[0] = pk8[4]; pa1.u[1] = pk8[5]; pa1.u[2] = pk8[6]; pa1.u[3] = pk8[7];

            if (!defer) {
                #pragma unroll
                for (int r = 0; r < 16; ++r) { o0[r] *= alpha; o1[r] *= alpha; }
            }

            // O^T += V^T * P  (A = V^T rows d, B = P cols q)
            #pragma unroll
            for (int sl = 0; sl < 2; ++sl) {
                const bf16x8 pf = sl == 0 ? pa0.v : pa1.v;
                const int cb = s * 64 + sl * 32 + hi * 16;
                bf16x8 va = *(const bf16x8*)(vb + lq * 128 + (cb ^ ((lq & 7) << 4)));
                bf16x8 vc = *(const bf16x8*)(vb + (lq + 32) * 128 + (cb ^ ((lq & 7) << 4)));
                o0 = __builtin_amdgcn_mfma_f32_32x32x16_bf16(va, pf, o0, 0, 0, 0);
                o1 = __builtin_amdgcn_mfma_f32_32x32x16_bf16(vc, pf, o1, 0, 0, 0);
            }
        }
        __syncthreads();
    }

    // epilogue: O^T[d][q] -> Op[b][t=q][h*64+d], normalize by lsum
    const float inv = 1.0f / lsum;
    const int b = bh / HH, h = bh % HH;
    ushort* dst = Op + ((size_t)(b * TT + qg)) * DD + h * ND;
    #pragma unroll
    for (int g = 0; g < 4; ++g) {
        ushort4 w0, w1;
        w0.x = f2bf(o0[4 * g + 0] * inv); w0.y = f2bf(o0[4 * g + 1] * inv);
        w0.z = f2bf(o0[4 * g + 2] * inv); w0.w = f2bf(o0[4 * g + 3] * inv);
        *(ushort4*)&dst[8 * g + 4 * hi] = w0;
        w1.x = f2bf(o1[4 * g + 0] * inv); w1.y = f2bf(o1[4 * g + 1] * inv);
        w1.z = f2bf(o1[4 * g + 2] * inv); w1.w = f2bf(o1[4 * g + 3] * inv);
        *(ushort4*)&dst[32 + 8 * g + 4 * hi] = w1;
    }
}

// ---------------------------------------------------------------------------
extern "C" void kernel_launch(void* const* d_in, const int* in_sizes, int n_in,
                              void* d_out, int out_size, void* d_ws, size_t ws_size,
                              hipStream_t stream)
{
    const float* q  = (const float*)d_in[0];
    const float* k  = (const float*)d_in[1];
    const float* v  = (const float*)d_in[2];
    const float* wq = (const float*)d_in[4];
    const float* bq = (const float*)d_in[5];
    const float* wk = (const float*)d_in[6];
    const float* bk = (const float*)d_in[7];
    const float* wv = (const float*)d_in[8];
    const float* bv = (const float*)d_in[9];
    const float* wo = (const float*)d_in[10];
    const float* fc = (const float*)d_in[11];
    const float* fs = (const float*)d_in[12];
    float* out = (float*)d_out;

    ushort* qB  = (ushort*)d_ws;           // [M][D] bf16
    ushort* kB  = qB  + (size_t)MM * DD;
    ushort* vB  = kB  + (size_t)MM * DD;
    ushort* wqT = vB  + (size_t)MM * DD;   // [n][k] bf16
    ushort* wkT = wqT + (size_t)DD * DD;
    ushort* wvT = wkT + (size_t)DD * DD;
    ushort* woT = wvT + (size_t)DD * DD;
    ushort* Qh  = woT + (size_t)DD * DD;   // [B,H,T,ND] bf16
    ushort* Kh  = Qh  + (size_t)MM * DD;
    ushort* Vh  = Kh  + (size_t)MM * DD;
    ushort* VhT = kB;                      // alias: kB dead after QKV GEMM
    ushort* Op  = qB;                      // alias: qB dead after QKV GEMM

    conv_x3<<<dim3(MM * DD / 4 / 256, 1, 3), 256, 0, stream>>>(q, k, v, qB, kB, vB);
    conv_wT<<<dim3(DD / 64, DD / 64, 4), 256, 0, stream>>>(wq, wk, wv, wo, wqT, wkT, wvT, woT);

    GArgs aq{qB, wqT, bq, (void*)Qh};
    GArgs ak{kB, wkT, bk, (void*)Kh};
    GArgs av{vB, wvT, bv, (void*)Vh};
    gemm_bf16<0><<<dim3(DD / 128, MM / 128, 3), 256, 0, stream>>>(aq, ak, av);

    rope_bf16<<<dim3(BB * HH * TT * 32 / 256), 256, 0, stream>>>(Qh, Kh, fc, fs);
    transpose_v<<<dim3(TT / 64, BB * HH), 256, 0, stream>>>(Vh, VhT);

    attn_mfma2<<<dim3(TT / 128, BB * HH), 256, 0, stream>>>(Qh, Kh, VhT, Op);

    GArgs ao{Op, woT, nullptr, (void*)out};
    gemm_bf16<1><<<dim3(DD / 128, MM / 128, 1), 256, 0, stream>>>(ao, ao, ao);
}

// Round 4
// 133.788 us; speedup vs baseline: 9.7039x; 1.1266x over previous
//
#include <hip/hip_runtime.h>
#include <hip/hip_bf16.h>
#include <math.h>

#define BB 2
#define TT 2048
#define DD 768
#define HH 12
#define ND 64
#define MM (BB*TT)   // 4096

typedef __attribute__((ext_vector_type(8))) short bf16x8;
typedef __attribute__((ext_vector_type(4))) float f32x4;
typedef __attribute__((ext_vector_type(16))) float f32x16;

__device__ __forceinline__ float bf2f(ushort u) {
    union { unsigned int i; float f; } v; v.i = ((unsigned int)u) << 16; return v.f;
}
__device__ __forceinline__ ushort f2bf(float f) {
    union { float f; unsigned int i; } v; v.f = f;
    unsigned int r = v.i + 0x7FFF + ((v.i >> 16) & 1);   // RNE
    return (ushort)(r >> 16);
}

// async global->LDS, 16B per lane. LDS base must be wave-uniform; HW adds lane*16.
__device__ __forceinline__ void cp16(void* lds, const void* g) {
    __builtin_amdgcn_global_load_lds(
        (const __attribute__((address_space(1))) void*)g,
        (__attribute__((address_space(3))) void*)lds, 16, 0, 0);
}

// 2^x via raw v_exp_f32 (single TRANS instruction)
__device__ __forceinline__ float fexp2(float x) {
    float r; asm("v_exp_f32 %0, %1" : "=v"(r) : "v"(x)); return r;
}
// pack two f32 -> 2x bf16 in one dword (lo = a, hi = b)
__device__ __forceinline__ unsigned int pk_bf16(float a, float b) {
    unsigned int r; asm("v_cvt_pk_bf16_f32 %0, %1, %2" : "=v"(r) : "v"(a), "v"(b)); return r;
}

// swap upper 32 lanes of a with lower 32 lanes of b
__device__ __forceinline__ void plswap(unsigned int& a, unsigned int& b) {
#if __has_builtin(__builtin_amdgcn_permlane32_swap)
    auto r = __builtin_amdgcn_permlane32_swap(a, b, false, false);
    a = r[0]; b = r[1];
#else
    unsigned int sa = __shfl_xor((int)a, 32), sb = __shfl_xor((int)b, 32);
    bool hi = (threadIdx.x & 63) >= 32;
    unsigned int na = hi ? sb : a, nb = hi ? b : sa;
    a = na; b = nb;
#endif
}
// value of x at lane^32 (both lanes get partner's value)
__device__ __forceinline__ float partner32(float x, int hi) {
#if __has_builtin(__builtin_amdgcn_permlane32_swap)
    unsigned int u = __float_as_uint(x);
    auto r = __builtin_amdgcn_permlane32_swap(u, u, false, false);
    return __uint_as_float(hi ? r[0] : r[1]);
#else
    return __shfl_xor(x, 32);
#endif
}

#define QSCALE 0.18033688011112043f   // 0.125 * log2(e)

// ---------------------------------------------------------------------------
// f32 -> bf16 conversion for q,k,v (layout preserved)
// ---------------------------------------------------------------------------
__global__ void conv_x3(const float* __restrict__ x0, const float* __restrict__ x1,
                        const float* __restrict__ x2,
                        ushort* __restrict__ o0, ushort* __restrict__ o1,
                        ushort* __restrict__ o2)
{
    const float* x = blockIdx.z == 0 ? x0 : (blockIdx.z == 1 ? x1 : x2);
    ushort* o = blockIdx.z == 0 ? o0 : (blockIdx.z == 1 ? o1 : o2);
    int i = (blockIdx.x * 256 + threadIdx.x) * 4;
    if (i >= MM * DD) return;
    float4 v = *(const float4*)&x[i];
    ushort4 r;
    r.x = f2bf(v.x); r.y = f2bf(v.y); r.z = f2bf(v.z); r.w = f2bf(v.w);
    *(ushort4*)&o[i] = r;
}

// ---------------------------------------------------------------------------
// weights f32 [k][n] -> bf16 transposed [n][k]
// ---------------------------------------------------------------------------
__global__ __launch_bounds__(256) void conv_wT(const float* __restrict__ w0, const float* __restrict__ w1,
                        const float* __restrict__ w2, const float* __restrict__ w3,
                        ushort* __restrict__ o0, ushort* __restrict__ o1,
                        ushort* __restrict__ o2, ushort* __restrict__ o3)
{
    __shared__ ushort tile[64][72];
    const float* w = blockIdx.z == 0 ? w0 : blockIdx.z == 1 ? w1 : blockIdx.z == 2 ? w2 : w3;
    ushort* o = blockIdx.z == 0 ? o0 : blockIdx.z == 1 ? o1 : blockIdx.z == 2 ? o2 : o3;
    const int k0 = blockIdx.y * 64, n0 = blockIdx.x * 64;
    #pragma unroll
    for (int it = 0; it < 4; ++it) {
        int e = (threadIdx.x + it * 256) * 4;
        int r = e >> 6, c = e & 63;
        float4 v = *(const float4*)&w[(size_t)(k0 + r) * DD + n0 + c];
        tile[c + 0][r] = f2bf(v.x);
        tile[c + 1][r] = f2bf(v.y);
        tile[c + 2][r] = f2bf(v.z);
        tile[c + 3][r] = f2bf(v.w);
    }
    __syncthreads();
    #pragma unroll
    for (int it = 0; it < 4; ++it) {
        int e = (threadIdx.x + it * 256) * 4;
        int nr = e >> 6, kc = e & 63;
        ushort4 r4;
        r4.x = tile[nr][kc + 0];
        r4.y = tile[nr][kc + 1];
        r4.z = tile[nr][kc + 2];
        r4.w = tile[nr][kc + 3];
        *(ushort4*)&o[(size_t)(n0 + nr) * DD + k0 + kc] = r4;
    }
}

// ---------------------------------------------------------------------------
// MFMA GEMM: A[M=4096][K=768] bf16 x WT[N][K] bf16.
// MODE 0: out bf16 head layout [B,H,T,ND] + f32 bias, optional fused RoPE
//         (rope=1: rope; rope=2: rope + QSCALE pre-scale for attn exp2 domain)
// MODE 1: out f32 flat [M][N], no bias (final projection)
// 128x128 tile, BK=32, 4 waves of 64x64, 2-phase prefetch.
// ---------------------------------------------------------------------------
struct GArgs { const ushort* x; const ushort* wt; const float* bias; void* out;
               const float* cT; const float* sT; int rope; };

template<int MODE>
__global__ __launch_bounds__(256) void gemm_bf16(GArgs a0, GArgs a1, GArgs a2)
{
    __shared__ __align__(16) ushort As[2][128 * 32];
    __shared__ __align__(16) ushort Bs[2][128 * 32];
    GArgs ga = (blockIdx.z == 0) ? a0 : (blockIdx.z == 1 ? a1 : a2);
    const int tid = threadIdx.x;
    const int w = tid >> 6, l = tid & 63;
    const int wr = w >> 1, wc = w & 1;
    const int n0 = blockIdx.x * 128, m0 = blockIdx.y * 128;

    f32x4 acc[4][4] = {};

    auto stage = [&](int buf, int k0) {
        #pragma unroll
        for (int it = 0; it < 2; ++it) {
            int o = it * 4096 + w * 1024 + l * 16;
            int row = o >> 6, kb = o & 63;
            cp16((char*)&As[buf][0] + it * 4096 + w * 1024,
                 (const char*)ga.x + (size_t)(m0 + row) * (DD * 2) + k0 * 2 + kb);
            cp16((char*)&Bs[buf][0] + it * 4096 + w * 1024,
                 (const char*)ga.wt + (size_t)(n0 + row) * (DD * 2) + k0 * 2 + kb);
        }
    };
    stage(0, 0);
    __syncthreads();
    const int NK = DD / 32;
    for (int t = 0; t < NK; ++t) {
        const int cur = t & 1;
        if (t + 1 < NK) stage(cur ^ 1, (t + 1) * 32);
        const char* ab = (const char*)&As[cur][0];
        const char* bb = (const char*)&Bs[cur][0];
        bf16x8 af[4], bfr[4];
        #pragma unroll
        for (int i = 0; i < 4; ++i)
            af[i] = *(const bf16x8*)(ab + (64 * wr + 16 * i + (l & 15)) * 64 + (l >> 4) * 16);
        #pragma unroll
        for (int j = 0; j < 4; ++j)
            bfr[j] = *(const bf16x8*)(bb + (64 * wc + 16 * j + (l & 15)) * 64 + (l >> 4) * 16);
        #pragma unroll
        for (int i = 0; i < 4; ++i)
            #pragma unroll
            for (int j = 0; j < 4; ++j)
                acc[i][j] = __builtin_amdgcn_mfma_f32_16x16x32_bf16(af[i], bfr[j], acc[i][j], 0, 0, 0);
        __syncthreads();
    }
    #pragma unroll
    for (int i = 0; i < 4; ++i) {
        #pragma unroll
        for (int j = 0; j < 4; ++j) {
            #pragma unroll
            for (int r = 0; r < 4; ++r) {
                const int m = m0 + 64 * wr + 16 * i + (l >> 4) * 4 + r;
                const int n = n0 + 64 * wc + 16 * j + (l & 15);
                float v = acc[i][j][r];
                if (MODE == 0) {
                    v += ga.bias[n];
                    const int tt = m & 2047;
                    if (ga.rope) {
                        const int d = n & 63;
                        const float c = ga.cT[tt * 32 + (d >> 1)];
                        const float s = ga.sT[tt * 32 + (d >> 1)];
                        const float p = __shfl_xor(v, 1);
                        v = (n & 1) ? (p * s + v * c) : (v * c - p * s);
                        if (ga.rope == 2) v *= QSCALE;
                    }
                    const int b = m >> 11;
                    const int h = n >> 6, d = n & 63;
                    ((ushort*)ga.out)[((size_t)(b * HH + h) * TT + tt) * ND + d] = f2bf(v);
                } else {
                    ((float*)ga.out)[(size_t)m * DD + n] = v;
                }
            }
        }
    }
}

// ---------------------------------------------------------------------------
// Vh [bh][t][d] -> VhT [bh][d][t]
// ---------------------------------------------------------------------------
__global__ __launch_bounds__(256) void transpose_v(const ushort* __restrict__ Vh,
                                                   ushort* __restrict__ VhT)
{
    __shared__ ushort tile[64][72];
    const int t0 = blockIdx.x * 64, bh = blockIdx.y;
    const ushort* src = Vh + ((size_t)bh * TT + t0) * ND;
    #pragma unroll
    for (int it = 0; it < 4; ++it) {
        int e = (threadIdx.x + it * 256) * 4;
        int r = e >> 6, c = e & 63;
        ushort4 v = *(const ushort4*)&src[r * ND + c];
        tile[r][c + 0] = v.x; tile[r][c + 1] = v.y;
        tile[r][c + 2] = v.z; tile[r][c + 3] = v.w;
    }
    __syncthreads();
    #pragma unroll
    for (int it = 0; it < 4; ++it) {
        int e = (threadIdx.x + it * 256) * 4;
        int d = e >> 6, tc = e & 63;
        ushort4 r4;
        r4.x = tile[tc + 0][d]; r4.y = tile[tc + 1][d];
        r4.z = tile[tc + 2][d]; r4.w = tile[tc + 3][d];
        *(ushort4*)&VhT[((size_t)bh * ND + d) * TT + t0 + tc] = r4;
    }
}

// ---------------------------------------------------------------------------
// MFMA flash attention, 32x32 swapped-operand structure + in-block KV-split.
// Block = 512 threads (8 waves), 128 q rows. Wave w: q-sub (w&3)*32 rows,
// kv-half (w>>2). Half h covers kv tiles [h*(qblk+1), (h+1)*(qblk+1)) of 64
// -- exactly balanced. Each half has its own double-buffered swizzled LDS.
// Partials (m,l,O) merged through LDS at the end.
// ---------------------------------------------------------------------------
__global__ __launch_bounds__(512) void attn_mfma3(const ushort* __restrict__ Qh,
                                                  const ushort* __restrict__ Kh,
                                                  const ushort* __restrict__ VhT,
                                                  ushort* __restrict__ Op)
{
    __shared__ __align__(16) ushort Ks[2][2][4096];   // [kvhalf][buf][64kv x 64d] swizzled
    __shared__ __align__(16) ushort Vs[2][2][4096];   // [kvhalf][buf][64d x 64kv] swizzled
    const int tid = threadIdx.x;
    const int w = tid >> 6, l = tid & 63;
    const int lq = l & 31, hi = l >> 5;
    const int qs = w & 3;                 // q subgroup (32 rows)
    const int kvh = w >> 2;               // kv half
    const int qblk = gridDim.x - 1 - blockIdx.x;    // longest blocks first
    const int q0 = qblk * 128;
    const int bh = blockIdx.y;
    const int q0w = q0 + qs * 32;
    const int qg = q0w + lq;              // this lane's q row
    const int ntH = qblk + 1;             // kv tiles per half
    const int kvbase = kvh * ntH * 64;

    const ushort* Qg = Qh + ((size_t)bh * TT + q0w) * ND;
    const ushort* Kg = Kh + (size_t)bh * TT * ND;
    const ushort* Vg = VhT + (size_t)bh * ND * TT;

    // Q fragments from global (B-operand: lane holds q row lq, d = ks*16+hi*8+e)
    bf16x8 qf[4];
    #pragma unroll
    for (int ks = 0; ks < 4; ++ks)
        qf[ks] = *(const bf16x8*)((const char*)Qg + lq * 128 + ks * 32 + hi * 16);

    // stage one 64-kv tile for this half (4 waves x 2 cp16 x 64 lanes x 16B = 16KB)
    auto stageKV = [&](int buf, int kv0) {
        #pragma unroll
        for (int it = 0; it < 2; ++it) {
            int o = it * 4096 + qs * 1024 + l * 16;
            int row = o >> 7, inner = o & 127;
            int swz = inner ^ ((row & 7) << 4);
            cp16((char*)&Ks[kvh][buf][0] + it * 4096 + qs * 1024,
                 (const char*)Kg + (size_t)(kv0 + row) * 128 + swz);
            cp16((char*)&Vs[kvh][buf][0] + it * 4096 + qs * 1024,
                 (const char*)Vg + (size_t)row * (TT * 2) + kv0 * 2 + swz);
        }
    };

    float m = -1e30f, lsum = 0.f;
    f32x16 o0 = {}, o1 = {};

    stageKV(0, kvbase);
    __syncthreads();
    for (int t = 0; t < ntH; ++t) {
        const int cur = t & 1;
        if (t + 1 < ntH) stageKV(cur ^ 1, kvbase + (t + 1) * 64);
        const char* kb = (const char*)&Ks[kvh][cur][0];
        const char* vb = (const char*)&Vs[kvh][cur][0];
        #pragma unroll
        for (int s = 0; s < 2; ++s) {
            const int kv0s = kvbase + t * 64 + s * 32;
            if (kv0s > q0w + 31) continue;          // fully masked (wave-uniform)

            // S^T[kv][q] over this 32-kv subtile
            f32x16 st = {};
            #pragma unroll
            for (int ks = 0; ks < 4; ++ks) {
                bf16x8 kf = *(const bf16x8*)(kb + (s * 32 + lq) * 128 +
                                             ((ks * 32 + hi * 16) ^ ((lq & 7) << 4)));
                st = __builtin_amdgcn_mfma_f32_32x32x16_bf16(kf, qf[ks], st, 0, 0, 0);
            }

            // causal mask + tile max (S already in log2 domain via Q pre-scale)
            float tm = -1e30f;
            if (kv0s + 31 > q0w) {
                #pragma unroll
                for (int r = 0; r < 16; ++r) {
                    const int kvg = kv0s + (r & 3) + 8 * (r >> 2) + 4 * hi;
                    float x = (kvg <= qg) ? st[r] : -1e30f;
                    st[r] = x;
                    tm = fmaxf(tm, x);
                }
            } else {
                #pragma unroll
                for (int r = 0; r < 16; ++r) tm = fmaxf(tm, st[r]);
            }
            tm = fmaxf(tm, partner32(tm, hi));

            // defer-max (T13): skip rescale if max growth <= 8 nats (11.5 log2)
            const bool defer = __all(tm <= m + 11.5f);
            float alpha = 1.f;
            if (!defer) {
                const float nm = fmaxf(m, tm);
                alpha = fexp2(m - nm);
                m = nm;
            }

            // P = exp2(S - m), rowsum, pack to bf16 pairs
            float rs = 0.f;
            unsigned int pk8[8];
            #pragma unroll
            for (int i = 0; i < 8; ++i) {
                const float p0 = fexp2(st[2 * i + 0] - m);
                const float p1 = fexp2(st[2 * i + 1] - m);
                rs += p0 + p1;
                pk8[i] = pk_bf16(p0, p1);
            }
            rs += partner32(rs, hi);
            lsum = lsum * alpha + rs;

            // rearrange into PV B-fragments: lane q, kv = slice*16 + hi*8 + e
            plswap(pk8[0], pk8[2]);
            plswap(pk8[1], pk8[3]);
            plswap(pk8[4], pk8[6]);
            plswap(pk8[5], pk8[7]);
            union { unsigned int u[4]; bf16x8 v; } pa0, pa1;
            pa0.u[0] = pk8[0]; pa0.u[1] = pk8[1]; pa0.u[2] = pk8[2]; pa0.u[3] = pk8[3];
            pa1.u[0] = pk8[4]; pa1.u[1] = pk8[5]; pa1.u[2] = pk8[6]; pa1.u[3] = pk8[7];

            if (!defer) {
                #pragma unroll
                for (int r = 0; r < 16; ++r) { o0[r] *= alpha; o1[r] *= alpha; }
            }

            // O^T += V^T * P  (A = V^T rows d, B = P cols q)
            #pragma unroll
            for (int sl = 0; sl < 2; ++sl) {
                const bf16x8 pf = sl == 0 ? pa0.v : pa1.v;
                const int cb = s * 64 + sl * 32 + hi * 16;
                bf16x8 va = *(const bf16x8*)(vb + lq * 128 + (cb ^ ((lq & 7) << 4)));
                bf16x8 vc = *(const bf16x8*)(vb + (lq + 32) * 128 + (cb ^ ((lq & 7) << 4)));
                o0 = __builtin_amdgcn_mfma_f32_32x32x16_bf16(va, pf, o0, 0, 0, 0);
                o1 = __builtin_amdgcn_mfma_f32_32x32x16_bf16(vc, pf, o1, 0, 0, 0);
            }
        }
        __syncthreads();
    }

    // ---- merge kv halves through LDS ----
    float* xO  = (float*)&Ks[0][0][0];    // 4 regions x 8KB = 32KB ([reg][lane])
    float* xML = (float*)&Vs[0][0][0];    // m,l per q-sub
    if (kvh == 1) {
        float* dst = xO + qs * 2048;
        #pragma unroll
        for (int r = 0; r < 16; ++r) {
            dst[r * 64 + l] = o0[r];
            dst[(r + 16) * 64 + l] = o1[r];
        }
        if (hi == 0) { xML[qs * 64 + lq] = m; xML[qs * 64 + 32 + lq] = lsum; }
    }
    __syncthreads();
    if (kvh == 0) {
        const float* src = xO + qs * 2048;
        const float m1 = xML[qs * 64 + lq];
        const float l1 = xML[qs * 64 + 32 + lq];
        const float ms = fmaxf(m, m1);
        const float a0 = fexp2(m - ms), a1 = fexp2(m1 - ms);
        const float inv = 1.0f / (lsum * a0 + l1 * a1);
        const int b = bh / HH, h = bh % HH;
        ushort* dst = Op + ((size_t)(b * TT + qg)) * DD + h * ND;
        #pragma unroll
        for (int g = 0; g < 4; ++g) {
            ushort4 w0, w1;
            w0.x = f2bf((o0[4 * g + 0] * a0 + src[(4 * g + 0) * 64 + l] * a1) * inv);
            w0.y = f2bf((o0[4 * g + 1] * a0 + src[(4 * g + 1) * 64 + l] * a1) * inv);
            w0.z = f2bf((o0[4 * g + 2] * a0 + src[(4 * g + 2) * 64 + l] * a1) * inv);
            w0.w = f2bf((o0[4 * g + 3] * a0 + src[(4 * g + 3) * 64 + l] * a1) * inv);
            *(ushort4*)&dst[8 * g + 4 * hi] = w0;
            w1.x = f2bf((o1[4 * g + 0] * a0 + src[(16 + 4 * g + 0) * 64 + l] * a1) * inv);
            w1.y = f2bf((o1[4 * g + 1] * a0 + src[(16 + 4 * g + 1) * 64 + l] * a1) * inv);
            w1.z = f2bf((o1[4 * g + 2] * a0 + src[(16 + 4 * g + 2) * 64 + l] * a1) * inv);
            w1.w = f2bf((o1[4 * g + 3] * a0 + src[(16 + 4 * g + 3) * 64 + l] * a1) * inv);
            *(ushort4*)&dst[32 + 8 * g + 4 * hi] = w1;
        }
    }
}

// ---------------------------------------------------------------------------
extern "C" void kernel_launch(void* const* d_in, const int* in_sizes, int n_in,
                              void* d_out, int out_size, void* d_ws, size_t ws_size,
                              hipStream_t stream)
{
    const float* q  = (const float*)d_in[0];
    const float* k  = (const float*)d_in[1];
    const float* v  = (const float*)d_in[2];
    const float* wq = (const float*)d_in[4];
    const float* bq = (const float*)d_in[5];
    const float* wk = (const float*)d_in[6];
    const float* bk = (const float*)d_in[7];
    const float* wv = (const float*)d_in[8];
    const float* bv = (const float*)d_in[9];
    const float* wo = (const float*)d_in[10];
    const float* fc = (const float*)d_in[11];
    const float* fs = (const float*)d_in[12];
    float* out = (float*)d_out;

    ushort* qB  = (ushort*)d_ws;           // [M][D] bf16
    ushort* kB  = qB  + (size_t)MM * DD;
    ushort* vB  = kB  + (size_t)MM * DD;
    ushort* wqT = vB  + (size_t)MM * DD;   // [n][k] bf16
    ushort* wkT = wqT + (size_t)DD * DD;
    ushort* wvT = wkT + (size_t)DD * DD;
    ushort* woT = wvT + (size_t)DD * DD;
    ushort* Qh  = woT + (size_t)DD * DD;   // [B,H,T,ND] bf16
    ushort* Kh  = Qh  + (size_t)MM * DD;
    ushort* Vh  = Kh  + (size_t)MM * DD;
    ushort* VhT = kB;                      // alias: kB dead after QKV GEMM
    ushort* Op  = qB;                      // alias: qB dead after QKV GEMM

    conv_x3<<<dim3(MM * DD / 4 / 256, 1, 3), 256, 0, stream>>>(q, k, v, qB, kB, vB);
    conv_wT<<<dim3(DD / 64, DD / 64, 4), 256, 0, stream>>>(wq, wk, wv, wo, wqT, wkT, wvT, woT);

    GArgs aq{qB, wqT, bq, (void*)Qh, fc, fs, 2};
    GArgs ak{kB, wkT, bk, (void*)Kh, fc, fs, 1};
    GArgs av{vB, wvT, bv, (void*)Vh, nullptr, nullptr, 0};
    gemm_bf16<0><<<dim3(DD / 128, MM / 128, 3), 256, 0, stream>>>(aq, ak, av);

    transpose_v<<<dim3(TT / 64, BB * HH), 256, 0, stream>>>(Vh, VhT);

    attn_mfma3<<<dim3(TT / 128, BB * HH), 512, 0, stream>>>(Qh, Kh, VhT, Op);

    GArgs ao{Op, woT, nullptr, (void*)out, nullptr, nullptr, 0};
    gemm_bf16<1><<<dim3(DD / 128, MM / 128, 1), 256, 0, stream>>>(ao, ao, ao);
}

// Round 5
// 120.668 us; speedup vs baseline: 10.7590x; 1.1087x over previous
//
#include <hip/hip_runtime.h>
#include <hip/hip_bf16.h>
#include <math.h>

#define BB 2
#define TT 2048
#define DD 768
#define HH 12
#define ND 64
#define MM (BB*TT)   // 4096

typedef __attribute__((ext_vector_type(8))) short bf16x8;
typedef __attribute__((ext_vector_type(4))) float f32x4;
typedef __attribute__((ext_vector_type(16))) float f32x16;

__device__ __forceinline__ float bf2f(ushort u) {
    union { unsigned int i; float f; } v; v.i = ((unsigned int)u) << 16; return v.f;
}
__device__ __forceinline__ ushort f2bf(float f) {
    union { float f; unsigned int i; } v; v.f = f;
    unsigned int r = v.i + 0x7FFF + ((v.i >> 16) & 1);   // RNE
    return (ushort)(r >> 16);
}

// async global->LDS, 16B per lane. LDS base must be wave-uniform; HW adds lane*16.
__device__ __forceinline__ void cp16(void* lds, const void* g) {
    __builtin_amdgcn_global_load_lds(
        (const __attribute__((address_space(1))) void*)g,
        (__attribute__((address_space(3))) void*)lds, 16, 0, 0);
}

// 2^x via raw v_exp_f32 (single TRANS instruction)
__device__ __forceinline__ float fexp2(float x) {
    float r; asm("v_exp_f32 %0, %1" : "=v"(r) : "v"(x)); return r;
}
// pack two f32 -> 2x bf16 in one dword (lo = a, hi = b)
__device__ __forceinline__ unsigned int pk_bf16(float a, float b) {
    unsigned int r; asm("v_cvt_pk_bf16_f32 %0, %1, %2" : "=v"(r) : "v"(a), "v"(b)); return r;
}

// swap upper 32 lanes of a with lower 32 lanes of b
__device__ __forceinline__ void plswap(unsigned int& a, unsigned int& b) {
#if __has_builtin(__builtin_amdgcn_permlane32_swap)
    auto r = __builtin_amdgcn_permlane32_swap(a, b, false, false);
    a = r[0]; b = r[1];
#else
    unsigned int sa = __shfl_xor((int)a, 32), sb = __shfl_xor((int)b, 32);
    bool hi = (threadIdx.x & 63) >= 32;
    unsigned int na = hi ? sb : a, nb = hi ? b : sa;
    a = na; b = nb;
#endif
}
// value of x at lane^32 (both lanes get partner's value)
__device__ __forceinline__ float partner32(float x, int hi) {
#if __has_builtin(__builtin_amdgcn_permlane32_swap)
    unsigned int u = __float_as_uint(x);
    auto r = __builtin_amdgcn_permlane32_swap(u, u, false, false);
    return __uint_as_float(hi ? r[0] : r[1]);
#else
    return __shfl_xor(x, 32);
#endif
}

#define QSCALE 0.18033688011112043f   // 0.125 * log2(e)

// ---------------------------------------------------------------------------
// f32 -> bf16 conversion for q,k,v (layout preserved)
// ---------------------------------------------------------------------------
__global__ void conv_x3(const float* __restrict__ x0, const float* __restrict__ x1,
                        const float* __restrict__ x2,
                        ushort* __restrict__ o0, ushort* __restrict__ o1,
                        ushort* __restrict__ o2)
{
    const float* x = blockIdx.z == 0 ? x0 : (blockIdx.z == 1 ? x1 : x2);
    ushort* o = blockIdx.z == 0 ? o0 : (blockIdx.z == 1 ? o1 : o2);
    int i = (blockIdx.x * 256 + threadIdx.x) * 4;
    if (i >= MM * DD) return;
    float4 v = *(const float4*)&x[i];
    ushort4 r;
    r.x = f2bf(v.x); r.y = f2bf(v.y); r.z = f2bf(v.z); r.w = f2bf(v.w);
    *(ushort4*)&o[i] = r;
}

// ---------------------------------------------------------------------------
// weights f32 [k][n] -> bf16 transposed [n][k]
// ---------------------------------------------------------------------------
__global__ __launch_bounds__(256) void conv_wT(const float* __restrict__ w0, const float* __restrict__ w1,
                        const float* __restrict__ w2, const float* __restrict__ w3,
                        ushort* __restrict__ o0, ushort* __restrict__ o1,
                        ushort* __restrict__ o2, ushort* __restrict__ o3)
{
    __shared__ ushort tile[64][72];
    const float* w = blockIdx.z == 0 ? w0 : blockIdx.z == 1 ? w1 : blockIdx.z == 2 ? w2 : w3;
    ushort* o = blockIdx.z == 0 ? o0 : blockIdx.z == 1 ? o1 : blockIdx.z == 2 ? o2 : o3;
    const int k0 = blockIdx.y * 64, n0 = blockIdx.x * 64;
    #pragma unroll
    for (int it = 0; it < 4; ++it) {
        int e = (threadIdx.x + it * 256) * 4;
        int r = e >> 6, c = e & 63;
        float4 v = *(const float4*)&w[(size_t)(k0 + r) * DD + n0 + c];
        tile[c + 0][r] = f2bf(v.x);
        tile[c + 1][r] = f2bf(v.y);
        tile[c + 2][r] = f2bf(v.z);
        tile[c + 3][r] = f2bf(v.w);
    }
    __syncthreads();
    #pragma unroll
    for (int it = 0; it < 4; ++it) {
        int e = (threadIdx.x + it * 256) * 4;
        int nr = e >> 6, kc = e & 63;
        ushort4 r4;
        r4.x = tile[nr][kc + 0];
        r4.y = tile[nr][kc + 1];
        r4.z = tile[nr][kc + 2];
        r4.w = tile[nr][kc + 3];
        *(ushort4*)&o[(size_t)(n0 + nr) * DD + k0 + kc] = r4;
    }
}

// ---------------------------------------------------------------------------
// MFMA GEMM: A[M=4096][K=768] bf16 x WT[N][K] bf16.
// MODE 0: out bf16 head layout [B,H,T,ND] + f32 bias, optional fused RoPE
//         (rope=1: rope; rope=2: rope + QSCALE pre-scale for attn exp2 domain)
// MODE 1: out f32 flat [M][N], no bias (final projection)
// 128x128 tile, BK=32, 4 waves of 64x64, 2-phase prefetch.
// ---------------------------------------------------------------------------
struct GArgs { const ushort* x; const ushort* wt; const float* bias; void* out;
               const float* cT; const float* sT; int rope; };

template<int MODE>
__global__ __launch_bounds__(256) void gemm_bf16(GArgs a0, GArgs a1, GArgs a2)
{
    __shared__ __align__(16) ushort As[2][128 * 32];
    __shared__ __align__(16) ushort Bs[2][128 * 32];
    GArgs ga = (blockIdx.z == 0) ? a0 : (blockIdx.z == 1 ? a1 : a2);
    const int tid = threadIdx.x;
    const int w = tid >> 6, l = tid & 63;
    const int wr = w >> 1, wc = w & 1;
    const int n0 = blockIdx.x * 128, m0 = blockIdx.y * 128;

    f32x4 acc[4][4] = {};

    auto stage = [&](int buf, int k0) {
        #pragma unroll
        for (int it = 0; it < 2; ++it) {
            int o = it * 4096 + w * 1024 + l * 16;
            int row = o >> 6, kb = o & 63;
            cp16((char*)&As[buf][0] + it * 4096 + w * 1024,
                 (const char*)ga.x + (size_t)(m0 + row) * (DD * 2) + k0 * 2 + kb);
            cp16((char*)&Bs[buf][0] + it * 4096 + w * 1024,
                 (const char*)ga.wt + (size_t)(n0 + row) * (DD * 2) + k0 * 2 + kb);
        }
    };
    stage(0, 0);
    __syncthreads();
    const int NK = DD / 32;
    for (int t = 0; t < NK; ++t) {
        const int cur = t & 1;
        if (t + 1 < NK) stage(cur ^ 1, (t + 1) * 32);
        const char* ab = (const char*)&As[cur][0];
        const char* bb = (const char*)&Bs[cur][0];
        bf16x8 af[4], bfr[4];
        #pragma unroll
        for (int i = 0; i < 4; ++i)
            af[i] = *(const bf16x8*)(ab + (64 * wr + 16 * i + (l & 15)) * 64 + (l >> 4) * 16);
        #pragma unroll
        for (int j = 0; j < 4; ++j)
            bfr[j] = *(const bf16x8*)(bb + (64 * wc + 16 * j + (l & 15)) * 64 + (l >> 4) * 16);
        #pragma unroll
        for (int i = 0; i < 4; ++i)
            #pragma unroll
            for (int j = 0; j < 4; ++j)
                acc[i][j] = __builtin_amdgcn_mfma_f32_16x16x32_bf16(af[i], bfr[j], acc[i][j], 0, 0, 0);
        __syncthreads();
    }
    #pragma unroll
    for (int i = 0; i < 4; ++i) {
        #pragma unroll
        for (int j = 0; j < 4; ++j) {
            #pragma unroll
            for (int r = 0; r < 4; ++r) {
                const int m = m0 + 64 * wr + 16 * i + (l >> 4) * 4 + r;
                const int n = n0 + 64 * wc + 16 * j + (l & 15);
                float v = acc[i][j][r];
                if (MODE == 0) {
                    v += ga.bias[n];
                    const int tt = m & 2047;
                    if (ga.rope) {
                        const int d = n & 63;
                        const float c = ga.cT[tt * 32 + (d >> 1)];
                        const float s = ga.sT[tt * 32 + (d >> 1)];
                        const float p = __shfl_xor(v, 1);
                        v = (n & 1) ? (p * s + v * c) : (v * c - p * s);
                        if (ga.rope == 2) v *= QSCALE;
                    }
                    const int b = m >> 11;
                    const int h = n >> 6, d = n & 63;
                    ((ushort*)ga.out)[((size_t)(b * HH + h) * TT + tt) * ND + d] = f2bf(v);
                } else {
                    ((float*)ga.out)[(size_t)m * DD + n] = v;
                }
            }
        }
    }
}

// ---------------------------------------------------------------------------
// Vh [bh][t][d] -> VhT [bh][d][t]
// ---------------------------------------------------------------------------
__global__ __launch_bounds__(256) void transpose_v(const ushort* __restrict__ Vh,
                                                   ushort* __restrict__ VhT)
{
    __shared__ ushort tile[64][72];
    const int t0 = blockIdx.x * 64, bh = blockIdx.y;
    const ushort* src = Vh + ((size_t)bh * TT + t0) * ND;
    #pragma unroll
    for (int it = 0; it < 4; ++it) {
        int e = (threadIdx.x + it * 256) * 4;
        int r = e >> 6, c = e & 63;
        ushort4 v = *(const ushort4*)&src[r * ND + c];
        tile[r][c + 0] = v.x; tile[r][c + 1] = v.y;
        tile[r][c + 2] = v.z; tile[r][c + 3] = v.w;
    }
    __syncthreads();
    #pragma unroll
    for (int it = 0; it < 4; ++it) {
        int e = (threadIdx.x + it * 256) * 4;
        int d = e >> 6, tc = e & 63;
        ushort4 r4;
        r4.x = tile[tc + 0][d]; r4.y = tile[tc + 1][d];
        r4.z = tile[tc + 2][d]; r4.w = tile[tc + 3][d];
        *(ushort4*)&VhT[((size_t)bh * ND + d) * TT + t0 + tc] = r4;
    }
}

// ---------------------------------------------------------------------------
// MFMA flash attention, 32x32 swapped-operand + in-block KV-split + balanced
// static schedule. 1D grid of NTASK=384 tasks (16 qblk x 24 bh).
// Task rank r sorted by cost desc (qblk desc): n<256 -> r=n (heavy, one per
// CU); n>=256 -> r=639-n (lightest pair with heaviest CUs). Per-CU pair sums
// are ~constant -> makespan ~ longest single block.
// Block = 512 threads (8 waves), 128 q rows; wave = (q-sub, kv-half).
// Fused softmax: ONE chain per 64-kv tile (both 32-kv subtiles together).
// ---------------------------------------------------------------------------
#define NQB (TT/128)        // 16
#define NBH (BB*HH)         // 24
#define NTASK (NQB*NBH)     // 384
#define NCU 256

__global__ __launch_bounds__(512) void attn_mfma4(const ushort* __restrict__ Qh,
                                                  const ushort* __restrict__ Kh,
                                                  const ushort* __restrict__ VhT,
                                                  ushort* __restrict__ Op)
{
    __shared__ __align__(16) ushort Ks[2][2][4096];   // [kvhalf][buf][64kv x 64d] swizzled
    __shared__ __align__(16) ushort Vs[2][2][4096];   // [kvhalf][buf][64d x 64kv] swizzled
    const int tid = threadIdx.x;
    const int w = tid >> 6, l = tid & 63;
    const int lq = l & 31, hi = l >> 5;
    const int qs = w & 3;                 // q subgroup (32 rows)
    const int kvh = w >> 2;               // kv half

    const int n = blockIdx.x;
    const int r_ = (n < NCU) ? n : (NTASK - 1 + NCU - n);
    const int qblk = (NQB - 1) - r_ / NBH;
    const int bh = r_ % NBH;

    const int q0 = qblk * 128;
    const int q0w = q0 + qs * 32;
    const int qg = q0w + lq;              // this lane's q row
    const int ntH = qblk + 1;             // kv tiles per half
    const int kvbase = kvh * ntH * 64;

    const ushort* Qg = Qh + ((size_t)bh * TT + q0w) * ND;
    const ushort* Kg = Kh + (size_t)bh * TT * ND;
    const ushort* Vg = VhT + (size_t)bh * ND * TT;

    // Q fragments from global (B-operand: lane holds q row lq, d = ks*16+hi*8+e)
    bf16x8 qf[4];
    #pragma unroll
    for (int ks = 0; ks < 4; ++ks)
        qf[ks] = *(const bf16x8*)((const char*)Qg + lq * 128 + ks * 32 + hi * 16);

    // stage one 64-kv tile for this half (4 waves x 2 cp16-pairs x 64 lanes x 16B)
    auto stageKV = [&](int buf, int kv0) {
        #pragma unroll
        for (int it = 0; it < 2; ++it) {
            int o = it * 4096 + qs * 1024 + l * 16;
            int row = o >> 7, inner = o & 127;
            int swz = inner ^ ((row & 7) << 4);
            cp16((char*)&Ks[kvh][buf][0] + it * 4096 + qs * 1024,
                 (const char*)Kg + (size_t)(kv0 + row) * 128 + swz);
            cp16((char*)&Vs[kvh][buf][0] + it * 4096 + qs * 1024,
                 (const char*)Vg + (size_t)row * (TT * 2) + kv0 * 2 + swz);
        }
    };

    float m = -1e30f, lsum = 0.f;
    f32x16 o0 = {}, o1 = {};

    stageKV(0, kvbase);
    __syncthreads();
    for (int t = 0; t < ntH; ++t) {
        const int cur = t & 1;
        if (t + 1 < ntH) stageKV(cur ^ 1, kvbase + (t + 1) * 64);
        const char* kb = (const char*)&Ks[kvh][cur][0];
        const char* vb = (const char*)&Vs[kvh][cur][0];
        const int kvt = kvbase + t * 64;

        if (kvt <= q0w + 31) {
            const bool have1 = (kvt + 32 <= q0w + 31);   // wave-uniform

            // S^T[kv][q]: both 32-kv subtiles
            f32x16 st0 = {}, st1 = {};
            __builtin_amdgcn_s_setprio(1);
            #pragma unroll
            for (int ks = 0; ks < 4; ++ks) {
                bf16x8 kf = *(const bf16x8*)(kb + lq * 128 +
                                             ((ks * 32 + hi * 16) ^ ((lq & 7) << 4)));
                st0 = __builtin_amdgcn_mfma_f32_32x32x16_bf16(kf, qf[ks], st0, 0, 0, 0);
            }
            if (have1) {
                #pragma unroll
                for (int ks = 0; ks < 4; ++ks) {
                    bf16x8 kf = *(const bf16x8*)(kb + (32 + lq) * 128 +
                                                 ((ks * 32 + hi * 16) ^ ((lq & 7) << 4)));
                    st1 = __builtin_amdgcn_mfma_f32_32x32x16_bf16(kf, qf[ks], st1, 0, 0, 0);
                }
            }
            __builtin_amdgcn_s_setprio(0);

            // causal mask + tile max over all 64 kv (one chain per tile)
            float tm = -1e30f;
            if (kvt + 31 > q0w) {
                #pragma unroll
                for (int r = 0; r < 16; ++r) {
                    const int kvg = kvt + (r & 3) + 8 * (r >> 2) + 4 * hi;
                    float x = (kvg <= qg) ? st0[r] : -1e30f;
                    st0[r] = x;
                    tm = fmaxf(tm, x);
                }
            } else {
                #pragma unroll
                for (int r = 0; r < 16; ++r) tm = fmaxf(tm, st0[r]);
            }
            if (have1) {
                if (kvt + 63 > q0w) {
                    #pragma unroll
                    for (int r = 0; r < 16; ++r) {
                        const int kvg = kvt + 32 + (r & 3) + 8 * (r >> 2) + 4 * hi;
                        float x = (kvg <= qg) ? st1[r] : -1e30f;
                        st1[r] = x;
                        tm = fmaxf(tm, x);
                    }
                } else {
                    #pragma unroll
                    for (int r = 0; r < 16; ++r) tm = fmaxf(tm, st1[r]);
                }
            }
            tm = fmaxf(tm, partner32(tm, hi));

            // defer-max (T13): skip rescale if max growth <= 8 nats (11.5 log2)
            const bool defer = __all(tm <= m + 11.5f);
            float alpha = 1.f;
            if (!defer) {
                const float nm = fmaxf(m, tm);
                alpha = fexp2(m - nm);
                m = nm;
            }

            // P = exp2(S - m), pack to bf16 pairs, tree rowsum
            float ps[16];
            unsigned int pkA[8], pkB[8];
            #pragma unroll
            for (int i = 0; i < 8; ++i) {
                const float p0 = fexp2(st0[2 * i + 0] - m);
                const float p1 = fexp2(st0[2 * i + 1] - m);
                pkA[i] = pk_bf16(p0, p1);
                ps[i] = p0 + p1;
            }
            if (have1) {
                #pragma unroll
                for (int i = 0; i < 8; ++i) {
                    const float p0 = fexp2(st1[2 * i + 0] - m);
                    const float p1 = fexp2(st1[2 * i + 1] - m);
                    pkB[i] = pk_bf16(p0, p1);
                    ps[8 + i] = p0 + p1;
                }
            } else {
                #pragma unroll
                for (int i = 0; i < 8; ++i) { pkB[i] = 0; ps[8 + i] = 0.f; }
            }
            const float t0s = (ps[0] + ps[1]) + (ps[2] + ps[3]);
            const float t1s = (ps[4] + ps[5]) + (ps[6] + ps[7]);
            const float t2s = (ps[8] + ps[9]) + (ps[10] + ps[11]);
            const float t3s = (ps[12] + ps[13]) + (ps[14] + ps[15]);
            float rs = (t0s + t1s) + (t2s + t3s);
            rs += partner32(rs, hi);
            lsum = lsum * alpha + rs;

            // rearrange into PV B-fragments: lane q, kv = slice*16 + hi*8 + e
            plswap(pkA[0], pkA[2]); plswap(pkA[1], pkA[3]);
            plswap(pkA[4], pkA[6]); plswap(pkA[5], pkA[7]);
            if (have1) {
                plswap(pkB[0], pkB[2]); plswap(pkB[1], pkB[3]);
                plswap(pkB[4], pkB[6]); plswap(pkB[5], pkB[7]);
            }
            union { unsigned int u[4]; bf16x8 v; } pa0, pa1, pa2, pa3;
            pa0.u[0] = pkA[0]; pa0.u[1] = pkA[1]; pa0.u[2] = pkA[2]; pa0.u[3] = pkA[3];
            pa1.u[0] = pkA[4]; pa1.u[1] = pkA[5]; pa1.u[2] = pkA[6]; pa1.u[3] = pkA[7];
            pa2.u[0] = pkB[0]; pa2.u[1] = pkB[1]; pa2.u[2] = pkB[2]; pa2.u[3] = pkB[3];
            pa3.u[0] = pkB[4]; pa3.u[1] = pkB[5]; pa3.u[2] = pkB[6]; pa3.u[3] = pkB[7];

            if (!defer) {
                #pragma unroll
                for (int r = 0; r < 16; ++r) { o0[r] *= alpha; o1[r] *= alpha; }
            }

            // O^T += V^T * P  (A = V^T rows d, B = P cols q)
            __builtin_amdgcn_s_setprio(1);
            #pragma unroll
            for (int sl = 0; sl < 2; ++sl) {
                const bf16x8 pf = sl == 0 ? pa0.v : pa1.v;
                const int cb = sl * 32 + hi * 16;
                bf16x8 va = *(const bf16x8*)(vb + lq * 128 + (cb ^ ((lq & 7) << 4)));
                bf16x8 vc = *(const bf16x8*)(vb + (lq + 32) * 128 + (cb ^ ((lq & 7) << 4)));
                o0 = __builtin_amdgcn_mfma_f32_32x32x16_bf16(va, pf, o0, 0, 0, 0);
                o1 = __builtin_amdgcn_mfma_f32_32x32x16_bf16(vc, pf, o1, 0, 0, 0);
            }
            if (have1) {
                #pragma unroll
                for (int sl = 0; sl < 2; ++sl) {
                    const bf16x8 pf = sl == 0 ? pa2.v : pa3.v;
                    const int cb = 64 + sl * 32 + hi * 16;
                    bf16x8 va = *(const bf16x8*)(vb + lq * 128 + (cb ^ ((lq & 7) << 4)));
                    bf16x8 vc = *(const bf16x8*)(vb + (lq + 32) * 128 + (cb ^ ((lq & 7) << 4)));
                    o0 = __builtin_amdgcn_mfma_f32_32x32x16_bf16(va, pf, o0, 0, 0, 0);
                    o1 = __builtin_amdgcn_mfma_f32_32x32x16_bf16(vc, pf, o1, 0, 0, 0);
                }
            }
            __builtin_amdgcn_s_setprio(0);
        }
        __syncthreads();
    }

    // ---- merge kv halves through LDS ----
    float* xO  = (float*)&Ks[0][0][0];    // 4 regions x 8KB = 32KB ([reg][lane])
    float* xML = (float*)&Vs[0][0][0];    // m,l per q-sub
    if (kvh == 1) {
        float* dst = xO + qs * 2048;
        #pragma unroll
        for (int r = 0; r < 16; ++r) {
            dst[r * 64 + l] = o0[r];
            dst[(r + 16) * 64 + l] = o1[r];
        }
        if (hi == 0) { xML[qs * 64 + lq] = m; xML[qs * 64 + 32 + lq] = lsum; }
    }
    __syncthreads();
    if (kvh == 0) {
        const float* src = xO + qs * 2048;
        const float m1 = xML[qs * 64 + lq];
        const float l1 = xML[qs * 64 + 32 + lq];
        const float ms = fmaxf(m, m1);
        const float a0 = fexp2(m - ms), a1 = fexp2(m1 - ms);
        const float inv = 1.0f / (lsum * a0 + l1 * a1);
        const int b = bh / HH, h = bh % HH;
        ushort* dst = Op + ((size_t)(b * TT + qg)) * DD + h * ND;
        #pragma unroll
        for (int g = 0; g < 4; ++g) {
            ushort4 w0, w1;
            w0.x = f2bf((o0[4 * g + 0] * a0 + src[(4 * g + 0) * 64 + l] * a1) * inv);
            w0.y = f2bf((o0[4 * g + 1] * a0 + src[(4 * g + 1) * 64 + l] * a1) * inv);
            w0.z = f2bf((o0[4 * g + 2] * a0 + src[(4 * g + 2) * 64 + l] * a1) * inv);
            w0.w = f2bf((o0[4 * g + 3] * a0 + src[(4 * g + 3) * 64 + l] * a1) * inv);
            *(ushort4*)&dst[8 * g + 4 * hi] = w0;
            w1.x = f2bf((o1[4 * g + 0] * a0 + src[(16 + 4 * g + 0) * 64 + l] * a1) * inv);
            w1.y = f2bf((o1[4 * g + 1] * a0 + src[(16 + 4 * g + 1) * 64 + l] * a1) * inv);
            w1.z = f2bf((o1[4 * g + 2] * a0 + src[(16 + 4 * g + 2) * 64 + l] * a1) * inv);
            w1.w = f2bf((o1[4 * g + 3] * a0 + src[(16 + 4 * g + 3) * 64 + l] * a1) * inv);
            *(ushort4*)&dst[32 + 8 * g + 4 * hi] = w1;
        }
    }
}

// ---------------------------------------------------------------------------
extern "C" void kernel_launch(void* const* d_in, const int* in_sizes, int n_in,
                              void* d_out, int out_size, void* d_ws, size_t ws_size,
                              hipStream_t stream)
{
    const float* q  = (const float*)d_in[0];
    const float* k  = (const float*)d_in[1];
    const float* v  = (const float*)d_in[2];
    const float* wq = (const float*)d_in[4];
    const float* bq = (const float*)d_in[5];
    const float* wk = (const float*)d_in[6];
    const float* bk = (const float*)d_in[7];
    const float* wv = (const float*)d_in[8];
    const float* bv = (const float*)d_in[9];
    const float* wo = (const float*)d_in[10];
    const float* fc = (const float*)d_in[11];
    const float* fs = (const float*)d_in[12];
    float* out = (float*)d_out;

    ushort* qB  = (ushort*)d_ws;           // [M][D] bf16
    ushort* kB  = qB  + (size_t)MM * DD;
    ushort* vB  = kB  + (size_t)MM * DD;
    ushort* wqT = vB  + (size_t)MM * DD;   // [n][k] bf16
    ushort* wkT = wqT + (size_t)DD * DD;
    ushort* wvT = wkT + (size_t)DD * DD;
    ushort* woT = wvT + (size_t)DD * DD;
    ushort* Qh  = woT + (size_t)DD * DD;   // [B,H,T,ND] bf16
    ushort* Kh  = Qh  + (size_t)MM * DD;
    ushort* Vh  = Kh  + (size_t)MM * DD;
    ushort* VhT = kB;                      // alias: kB dead after QKV GEMM
    ushort* Op  = qB;                      // alias: qB dead after QKV GEMM

    conv_x3<<<dim3(MM * DD / 4 / 256, 1, 3), 256, 0, stream>>>(q, k, v, qB, kB, vB);
    conv_wT<<<dim3(DD / 64, DD / 64, 4), 256, 0, stream>>>(wq, wk, wv, wo, wqT, wkT, wvT, woT);

    GArgs aq{qB, wqT, bq, (void*)Qh, fc, fs, 2};
    GArgs ak{kB, wkT, bk, (void*)Kh, fc, fs, 1};
    GArgs av{vB, wvT, bv, (void*)Vh, nullptr, nullptr, 0};
    gemm_bf16<0><<<dim3(DD / 128, MM / 128, 3), 256, 0, stream>>>(aq, ak, av);

    transpose_v<<<dim3(TT / 64, BB * HH), 256, 0, stream>>>(Vh, VhT);

    attn_mfma4<<<dim3(NTASK), 512, 0, stream>>>(Qh, Kh, VhT, Op);

    GArgs ao{Op, woT, nullptr, (void*)out, nullptr, nullptr, 0};
    gemm_bf16<1><<<dim3(DD / 128, MM / 128, 1), 256, 0, stream>>>(ao, ao, ao);
}

// Round 6
// 108.417 us; speedup vs baseline: 11.9748x; 1.1130x over previous
//
#include <hip/hip_runtime.h>
#include <hip/hip_bf16.h>
#include <math.h>

#define BB 2
#define TT 2048
#define DD 768
#define HH 12
#define ND 64
#define MM (BB*TT)   // 4096

typedef __attribute__((ext_vector_type(8))) short bf16x8;
typedef __attribute__((ext_vector_type(4))) float f32x4;
typedef __attribute__((ext_vector_type(16))) float f32x16;

__device__ __forceinline__ float bf2f(ushort u) {
    union { unsigned int i; float f; } v; v.i = ((unsigned int)u) << 16; return v.f;
}
__device__ __forceinline__ ushort f2bf(float f) {
    union { float f; unsigned int i; } v; v.f = f;
    unsigned int r = v.i + 0x7FFF + ((v.i >> 16) & 1);   // RNE
    return (ushort)(r >> 16);
}

// async global->LDS, 16B per lane. LDS base must be wave-uniform; HW adds lane*16.
__device__ __forceinline__ void cp16(void* lds, const void* g) {
    __builtin_amdgcn_global_load_lds(
        (const __attribute__((address_space(1))) void*)g,
        (__attribute__((address_space(3))) void*)lds, 16, 0, 0);
}

// 2^x via raw v_exp_f32 (single TRANS instruction)
__device__ __forceinline__ float fexp2(float x) {
    float r; asm("v_exp_f32 %0, %1" : "=v"(r) : "v"(x)); return r;
}
// pack two f32 -> 2x bf16 in one dword (lo = a, hi = b)
__device__ __forceinline__ unsigned int pk_bf16(float a, float b) {
    unsigned int r; asm("v_cvt_pk_bf16_f32 %0, %1, %2" : "=v"(r) : "v"(a), "v"(b)); return r;
}

// swap upper 32 lanes of a with lower 32 lanes of b
__device__ __forceinline__ void plswap(unsigned int& a, unsigned int& b) {
#if __has_builtin(__builtin_amdgcn_permlane32_swap)
    auto r = __builtin_amdgcn_permlane32_swap(a, b, false, false);
    a = r[0]; b = r[1];
#else
    unsigned int sa = __shfl_xor((int)a, 32), sb = __shfl_xor((int)b, 32);
    bool hi = (threadIdx.x & 63) >= 32;
    unsigned int na = hi ? sb : a, nb = hi ? b : sa;
    a = na; b = nb;
#endif
}
// value of x at lane^32 (both lanes get partner's value)
__device__ __forceinline__ float partner32(float x, int hi) {
#if __has_builtin(__builtin_amdgcn_permlane32_swap)
    unsigned int u = __float_as_uint(x);
    auto r = __builtin_amdgcn_permlane32_swap(u, u, false, false);
    return __uint_as_float(hi ? r[0] : r[1]);
#else
    return __shfl_xor(x, 32);
#endif
}

#define QSCALE 0.18033688011112043f   // 0.125 * log2(e)

// ---------------------------------------------------------------------------
// f32 -> bf16 conversion for q,k,v (layout preserved)
// ---------------------------------------------------------------------------
__global__ void conv_x3(const float* __restrict__ x0, const float* __restrict__ x1,
                        const float* __restrict__ x2,
                        ushort* __restrict__ o0, ushort* __restrict__ o1,
                        ushort* __restrict__ o2)
{
    const float* x = blockIdx.z == 0 ? x0 : (blockIdx.z == 1 ? x1 : x2);
    ushort* o = blockIdx.z == 0 ? o0 : (blockIdx.z == 1 ? o1 : o2);
    int i = (blockIdx.x * 256 + threadIdx.x) * 4;
    if (i >= MM * DD) return;
    float4 v = *(const float4*)&x[i];
    ushort4 r;
    r.x = f2bf(v.x); r.y = f2bf(v.y); r.z = f2bf(v.z); r.w = f2bf(v.w);
    *(ushort4*)&o[i] = r;
}

// ---------------------------------------------------------------------------
// weights f32 [k][n] -> bf16 transposed [n][k]
// ---------------------------------------------------------------------------
__global__ __launch_bounds__(256) void conv_wT(const float* __restrict__ w0, const float* __restrict__ w1,
                        const float* __restrict__ w2, const float* __restrict__ w3,
                        ushort* __restrict__ o0, ushort* __restrict__ o1,
                        ushort* __restrict__ o2, ushort* __restrict__ o3)
{
    __shared__ ushort tile[64][72];
    const float* w = blockIdx.z == 0 ? w0 : blockIdx.z == 1 ? w1 : blockIdx.z == 2 ? w2 : w3;
    ushort* o = blockIdx.z == 0 ? o0 : blockIdx.z == 1 ? o1 : blockIdx.z == 2 ? o2 : o3;
    const int k0 = blockIdx.y * 64, n0 = blockIdx.x * 64;
    #pragma unroll
    for (int it = 0; it < 4; ++it) {
        int e = (threadIdx.x + it * 256) * 4;
        int r = e >> 6, c = e & 63;
        float4 v = *(const float4*)&w[(size_t)(k0 + r) * DD + n0 + c];
        tile[c + 0][r] = f2bf(v.x);
        tile[c + 1][r] = f2bf(v.y);
        tile[c + 2][r] = f2bf(v.z);
        tile[c + 3][r] = f2bf(v.w);
    }
    __syncthreads();
    #pragma unroll
    for (int it = 0; it < 4; ++it) {
        int e = (threadIdx.x + it * 256) * 4;
        int nr = e >> 6, kc = e & 63;
        ushort4 r4;
        r4.x = tile[nr][kc + 0];
        r4.y = tile[nr][kc + 1];
        r4.z = tile[nr][kc + 2];
        r4.w = tile[nr][kc + 3];
        *(ushort4*)&o[(size_t)(n0 + nr) * DD + k0 + kc] = r4;
    }
}

// ---------------------------------------------------------------------------
// MFMA GEMM: A[M=4096][K=768] bf16 x WT[N][K] bf16. Templated tile TM x TN,
// 4 waves in 2x2 (wave tile TM/2 x TN/2), BK=32, combined A+B LDS buffer,
// 2-phase prefetch. Small tiles -> many blocks (grid-starvation fix).
// MODE 0: out bf16 head layout [B,H,T,ND] + f32 bias, optional fused RoPE
// MODE 1: out f32 flat [M][N], no bias
// ---------------------------------------------------------------------------
struct GArgs { const ushort* x; const ushort* wt; const float* bias; void* out;
               const float* cT; const float* sT; int rope; };

template<int MODE, int TM, int TN>
__global__ __launch_bounds__(256) void gemm_bf16(GArgs a0, GArgs a1, GArgs a2)
{
    constexpr int WM = TM / 2, WN = TN / 2;
    constexpr int MF = WM / 16, NF = WN / 16;
    constexpr int BUFB = (TM + TN) * 64;      // bytes per buffer (A then B)
    constexpr int NPASS = BUFB / 4096;        // staging passes (4KB per pass)
    __shared__ __align__(16) ushort S[2][BUFB / 2];
    GArgs ga = (blockIdx.z == 0) ? a0 : (blockIdx.z == 1 ? a1 : a2);
    const int tid = threadIdx.x;
    const int w = tid >> 6, l = tid & 63;
    const int wr = w >> 1, wc = w & 1;
    const int n0 = blockIdx.x * TN, m0 = blockIdx.y * TM;

    f32x4 acc[MF][NF] = {};

    auto stage = [&](int buf, int k0) {
        #pragma unroll
        for (int it = 0; it < NPASS; ++it) {
            const int ob = it * 4096 + w * 1024;       // wave-uniform chunk base
            const int o = ob + l * 16;
            if (ob < TM * 64) {
                const int row = o >> 6, kb = o & 63;
                cp16((char*)&S[buf][0] + ob,
                     (const char*)ga.x + (size_t)(m0 + row) * (DD * 2) + k0 * 2 + kb);
            } else {
                const int o2 = o - TM * 64;
                const int row = o2 >> 6, kb = o2 & 63;
                cp16((char*)&S[buf][0] + ob,
                     (const char*)ga.wt + (size_t)(n0 + row) * (DD * 2) + k0 * 2 + kb);
            }
        }
    };
    stage(0, 0);
    __syncthreads();
    const int NK = DD / 32;
    for (int t = 0; t < NK; ++t) {
        const int cur = t & 1;
        if (t + 1 < NK) stage(cur ^ 1, (t + 1) * 32);
        const char* ab = (const char*)&S[cur][0];
        bf16x8 af[MF], bfr[NF];
        #pragma unroll
        for (int i = 0; i < MF; ++i)
            af[i] = *(const bf16x8*)(ab + (WM * wr + 16 * i + (l & 15)) * 64 + (l >> 4) * 16);
        #pragma unroll
        for (int j = 0; j < NF; ++j)
            bfr[j] = *(const bf16x8*)(ab + TM * 64 + (WN * wc + 16 * j + (l & 15)) * 64 + (l >> 4) * 16);
        #pragma unroll
        for (int i = 0; i < MF; ++i)
            #pragma unroll
            for (int j = 0; j < NF; ++j)
                acc[i][j] = __builtin_amdgcn_mfma_f32_16x16x32_bf16(af[i], bfr[j], acc[i][j], 0, 0, 0);
        __syncthreads();
    }
    #pragma unroll
    for (int i = 0; i < MF; ++i) {
        #pragma unroll
        for (int j = 0; j < NF; ++j) {
            #pragma unroll
            for (int r = 0; r < 4; ++r) {
                const int m = m0 + WM * wr + 16 * i + (l >> 4) * 4 + r;
                const int n = n0 + WN * wc + 16 * j + (l & 15);
                float v = acc[i][j][r];
                if (MODE == 0) {
                    v += ga.bias[n];
                    const int tt = m & 2047;
                    if (ga.rope) {
                        const int d = n & 63;
                        const float c = ga.cT[tt * 32 + (d >> 1)];
                        const float s = ga.sT[tt * 32 + (d >> 1)];
                        const float p = __shfl_xor(v, 1);
                        v = (n & 1) ? (p * s + v * c) : (v * c - p * s);
                        if (ga.rope == 2) v *= QSCALE;
                    }
                    const int b = m >> 11;
                    const int h = n >> 6, d = n & 63;
                    ((ushort*)ga.out)[((size_t)(b * HH + h) * TT + tt) * ND + d] = f2bf(v);
                } else {
                    ((float*)ga.out)[(size_t)m * DD + n] = v;
                }
            }
        }
    }
}

// ---------------------------------------------------------------------------
// Vh [bh][t][d] -> VhT [bh][d][t]
// ---------------------------------------------------------------------------
__global__ __launch_bounds__(256) void transpose_v(const ushort* __restrict__ Vh,
                                                   ushort* __restrict__ VhT)
{
    __shared__ ushort tile[64][72];
    const int t0 = blockIdx.x * 64, bh = blockIdx.y;
    const ushort* src = Vh + ((size_t)bh * TT + t0) * ND;
    #pragma unroll
    for (int it = 0; it < 4; ++it) {
        int e = (threadIdx.x + it * 256) * 4;
        int r = e >> 6, c = e & 63;
        ushort4 v = *(const ushort4*)&src[r * ND + c];
        tile[r][c + 0] = v.x; tile[r][c + 1] = v.y;
        tile[r][c + 2] = v.z; tile[r][c + 3] = v.w;
    }
    __syncthreads();
    #pragma unroll
    for (int it = 0; it < 4; ++it) {
        int e = (threadIdx.x + it * 256) * 4;
        int d = e >> 6, tc = e & 63;
        ushort4 r4;
        r4.x = tile[tc + 0][d]; r4.y = tile[tc + 1][d];
        r4.z = tile[tc + 2][d]; r4.w = tile[tc + 3][d];
        *(ushort4*)&VhT[((size_t)bh * ND + d) * TT + t0 + tc] = r4;
    }
}

// ---------------------------------------------------------------------------
// MFMA flash attention, 32x32 swapped-operand + in-block KV-split + balanced
// static schedule. 1D grid of NTASK=384 tasks (16 qblk x 24 bh).
// ---------------------------------------------------------------------------
#define NQB (TT/128)        // 16
#define NBH (BB*HH)         // 24
#define NTASK (NQB*NBH)     // 384
#define NCU 256

__global__ __launch_bounds__(512) void attn_mfma4(const ushort* __restrict__ Qh,
                                                  const ushort* __restrict__ Kh,
                                                  const ushort* __restrict__ VhT,
                                                  ushort* __restrict__ Op)
{
    __shared__ __align__(16) ushort Ks[2][2][4096];   // [kvhalf][buf][64kv x 64d] swizzled
    __shared__ __align__(16) ushort Vs[2][2][4096];   // [kvhalf][buf][64d x 64kv] swizzled
    const int tid = threadIdx.x;
    const int w = tid >> 6, l = tid & 63;
    const int lq = l & 31, hi = l >> 5;
    const int qs = w & 3;                 // q subgroup (32 rows)
    const int kvh = w >> 2;               // kv half

    const int n = blockIdx.x;
    const int r_ = (n < NCU) ? n : (NTASK - 1 + NCU - n);
    const int qblk = (NQB - 1) - r_ / NBH;
    const int bh = r_ % NBH;

    const int q0 = qblk * 128;
    const int q0w = q0 + qs * 32;
    const int qg = q0w + lq;              // this lane's q row
    const int ntH = qblk + 1;             // kv tiles per half
    const int kvbase = kvh * ntH * 64;

    const ushort* Qg = Qh + ((size_t)bh * TT + q0w) * ND;
    const ushort* Kg = Kh + (size_t)bh * TT * ND;
    const ushort* Vg = VhT + (size_t)bh * ND * TT;

    // Q fragments from global (B-operand: lane holds q row lq, d = ks*16+hi*8+e)
    bf16x8 qf[4];
    #pragma unroll
    for (int ks = 0; ks < 4; ++ks)
        qf[ks] = *(const bf16x8*)((const char*)Qg + lq * 128 + ks * 32 + hi * 16);

    // stage one 64-kv tile for this half (4 waves x 2 cp16-pairs x 64 lanes x 16B)
    auto stageKV = [&](int buf, int kv0) {
        #pragma unroll
        for (int it = 0; it < 2; ++it) {
            int o = it * 4096 + qs * 1024 + l * 16;
            int row = o >> 7, inner = o & 127;
            int swz = inner ^ ((row & 7) << 4);
            cp16((char*)&Ks[kvh][buf][0] + it * 4096 + qs * 1024,
                 (const char*)Kg + (size_t)(kv0 + row) * 128 + swz);
            cp16((char*)&Vs[kvh][buf][0] + it * 4096 + qs * 1024,
                 (const char*)Vg + (size_t)row * (TT * 2) + kv0 * 2 + swz);
        }
    };

    float m = -1e30f, lsum = 0.f;
    f32x16 o0 = {}, o1 = {};

    stageKV(0, kvbase);
    __syncthreads();
    for (int t = 0; t < ntH; ++t) {
        const int cur = t & 1;
        if (t + 1 < ntH) stageKV(cur ^ 1, kvbase + (t + 1) * 64);
        const char* kb = (const char*)&Ks[kvh][cur][0];
        const char* vb = (const char*)&Vs[kvh][cur][0];
        const int kvt = kvbase + t * 64;

        if (kvt <= q0w + 31) {
            const bool have1 = (kvt + 32 <= q0w + 31);   // wave-uniform

            // S^T[kv][q]: both 32-kv subtiles
            f32x16 st0 = {}, st1 = {};
            __builtin_amdgcn_s_setprio(1);
            #pragma unroll
            for (int ks = 0; ks < 4; ++ks) {
                bf16x8 kf = *(const bf16x8*)(kb + lq * 128 +
                                             ((ks * 32 + hi * 16) ^ ((lq & 7) << 4)));
                st0 = __builtin_amdgcn_mfma_f32_32x32x16_bf16(kf, qf[ks], st0, 0, 0, 0);
            }
            if (have1) {
                #pragma unroll
                for (int ks = 0; ks < 4; ++ks) {
                    bf16x8 kf = *(const bf16x8*)(kb + (32 + lq) * 128 +
                                                 ((ks * 32 + hi * 16) ^ ((lq & 7) << 4)));
                    st1 = __builtin_amdgcn_mfma_f32_32x32x16_bf16(kf, qf[ks], st1, 0, 0, 0);
                }
            }
            __builtin_amdgcn_s_setprio(0);

            // causal mask + tile max over all 64 kv (one chain per tile)
            float tm = -1e30f;
            if (kvt + 31 > q0w) {
                #pragma unroll
                for (int r = 0; r < 16; ++r) {
                    const int kvg = kvt + (r & 3) + 8 * (r >> 2) + 4 * hi;
                    float x = (kvg <= qg) ? st0[r] : -1e30f;
                    st0[r] = x;
                    tm = fmaxf(tm, x);
                }
            } else {
                #pragma unroll
                for (int r = 0; r < 16; ++r) tm = fmaxf(tm, st0[r]);
            }
            if (have1) {
                if (kvt + 63 > q0w) {
                    #pragma unroll
                    for (int r = 0; r < 16; ++r) {
                        const int kvg = kvt + 32 + (r & 3) + 8 * (r >> 2) + 4 * hi;
                        float x = (kvg <= qg) ? st1[r] : -1e30f;
                        st1[r] = x;
                        tm = fmaxf(tm, x);
                    }
                } else {
                    #pragma unroll
                    for (int r = 0; r < 16; ++r) tm = fmaxf(tm, st1[r]);
                }
            }
            tm = fmaxf(tm, partner32(tm, hi));

            // defer-max (T13): skip rescale if max growth <= 8 nats (11.5 log2)
            const bool defer = __all(tm <= m + 11.5f);
            float alpha = 1.f;
            if (!defer) {
                const float nm = fmaxf(m, tm);
                alpha = fexp2(m - nm);
                m = nm;
            }

            // P = exp2(S - m), pack to bf16 pairs, tree rowsum
            float ps[16];
            unsigned int pkA[8], pkB[8];
            #pragma unroll
            for (int i = 0; i < 8; ++i) {
                const float p0 = fexp2(st0[2 * i + 0] - m);
                const float p1 = fexp2(st0[2 * i + 1] - m);
                pkA[i] = pk_bf16(p0, p1);
                ps[i] = p0 + p1;
            }
            if (have1) {
                #pragma unroll
                for (int i = 0; i < 8; ++i) {
                    const float p0 = fexp2(st1[2 * i + 0] - m);
                    const float p1 = fexp2(st1[2 * i + 1] - m);
                    pkB[i] = pk_bf16(p0, p1);
                    ps[8 + i] = p0 + p1;
                }
            } else {
                #pragma unroll
                for (int i = 0; i < 8; ++i) { pkB[i] = 0; ps[8 + i] = 0.f; }
            }
            const float t0s = (ps[0] + ps[1]) + (ps[2] + ps[3]);
            const float t1s = (ps[4] + ps[5]) + (ps[6] + ps[7]);
            const float t2s = (ps[8] + ps[9]) + (ps[10] + ps[11]);
            const float t3s = (ps[12] + ps[13]) + (ps[14] + ps[15]);
            float rs = (t0s + t1s) + (t2s + t3s);
            rs += partner32(rs, hi);
            lsum = lsum * alpha + rs;

            // rearrange into PV B-fragments: lane q, kv = slice*16 + hi*8 + e
            plswap(pkA[0], pkA[2]); plswap(pkA[1], pkA[3]);
            plswap(pkA[4], pkA[6]); plswap(pkA[5], pkA[7]);
            if (have1) {
                plswap(pkB[0], pkB[2]); plswap(pkB[1], pkB[3]);
                plswap(pkB[4], pkB[6]); plswap(pkB[5], pkB[7]);
            }
            union { unsigned int u[4]; bf16x8 v; } pa0, pa1, pa2, pa3;
            pa0.u[0] = pkA[0]; pa0.u[1] = pkA[1]; pa0.u[2] = pkA[2]; pa0.u[3] = pkA[3];
            pa1.u[0] = pkA[4]; pa1.u[1] = pkA[5]; pa1.u[2] = pkA[6]; pa1.u[3] = pkA[7];
            pa2.u[0] = pkB[0]; pa2.u[1] = pkB[1]; pa2.u[2] = pkB[2]; pa2.u[3] = pkB[3];
            pa3.u[0] = pkB[4]; pa3.u[1] = pkB[5]; pa3.u[2] = pkB[6]; pa3.u[3] = pkB[7];

            if (!defer) {
                #pragma unroll
                for (int r = 0; r < 16; ++r) { o0[r] *= alpha; o1[r] *= alpha; }
            }

            // O^T += V^T * P  (A = V^T rows d, B = P cols q)
            __builtin_amdgcn_s_setprio(1);
            #pragma unroll
            for (int sl = 0; sl < 2; ++sl) {
                const bf16x8 pf = sl == 0 ? pa0.v : pa1.v;
                const int cb = sl * 32 + hi * 16;
                bf16x8 va = *(const bf16x8*)(vb + lq * 128 + (cb ^ ((lq & 7) << 4)));
                bf16x8 vc = *(const bf16x8*)(vb + (lq + 32) * 128 + (cb ^ ((lq & 7) << 4)));
                o0 = __builtin_amdgcn_mfma_f32_32x32x16_bf16(va, pf, o0, 0, 0, 0);
                o1 = __builtin_amdgcn_mfma_f32_32x32x16_bf16(vc, pf, o1, 0, 0, 0);
            }
            if (have1) {
                #pragma unroll
                for (int sl = 0; sl < 2; ++sl) {
                    const bf16x8 pf = sl == 0 ? pa2.v : pa3.v;
                    const int cb = 64 + sl * 32 + hi * 16;
                    bf16x8 va = *(const bf16x8*)(vb + lq * 128 + (cb ^ ((lq & 7) << 4)));
                    bf16x8 vc = *(const bf16x8*)(vb + (lq + 32) * 128 + (cb ^ ((lq & 7) << 4)));
                    o0 = __builtin_amdgcn_mfma_f32_32x32x16_bf16(va, pf, o0, 0, 0, 0);
                    o1 = __builtin_amdgcn_mfma_f32_32x32x16_bf16(vc, pf, o1, 0, 0, 0);
                }
            }
            __builtin_amdgcn_s_setprio(0);
        }
        __syncthreads();
    }

    // ---- merge kv halves through LDS ----
    float* xO  = (float*)&Ks[0][0][0];    // 4 regions x 8KB = 32KB ([reg][lane])
    float* xML = (float*)&Vs[0][0][0];    // m,l per q-sub
    if (kvh == 1) {
        float* dst = xO + qs * 2048;
        #pragma unroll
        for (int r = 0; r < 16; ++r) {
            dst[r * 64 + l] = o0[r];
            dst[(r + 16) * 64 + l] = o1[r];
        }
        if (hi == 0) { xML[qs * 64 + lq] = m; xML[qs * 64 + 32 + lq] = lsum; }
    }
    __syncthreads();
    if (kvh == 0) {
        const float* src = xO + qs * 2048;
        const float m1 = xML[qs * 64 + lq];
        const float l1 = xML[qs * 64 + 32 + lq];
        const float ms = fmaxf(m, m1);
        const float a0 = fexp2(m - ms), a1 = fexp2(m1 - ms);
        const float inv = 1.0f / (lsum * a0 + l1 * a1);
        const int b = bh / HH, h = bh % HH;
        ushort* dst = Op + ((size_t)(b * TT + qg)) * DD + h * ND;
        #pragma unroll
        for (int g = 0; g < 4; ++g) {
            ushort4 w0, w1;
            w0.x = f2bf((o0[4 * g + 0] * a0 + src[(4 * g + 0) * 64 + l] * a1) * inv);
            w0.y = f2bf((o0[4 * g + 1] * a0 + src[(4 * g + 1) * 64 + l] * a1) * inv);
            w0.z = f2bf((o0[4 * g + 2] * a0 + src[(4 * g + 2) * 64 + l] * a1) * inv);
            w0.w = f2bf((o0[4 * g + 3] * a0 + src[(4 * g + 3) * 64 + l] * a1) * inv);
            *(ushort4*)&dst[8 * g + 4 * hi] = w0;
            w1.x = f2bf((o1[4 * g + 0] * a0 + src[(16 + 4 * g + 0) * 64 + l] * a1) * inv);
            w1.y = f2bf((o1[4 * g + 1] * a0 + src[(16 + 4 * g + 1) * 64 + l] * a1) * inv);
            w1.z = f2bf((o1[4 * g + 2] * a0 + src[(16 + 4 * g + 2) * 64 + l] * a1) * inv);
            w1.w = f2bf((o1[4 * g + 3] * a0 + src[(16 + 4 * g + 3) * 64 + l] * a1) * inv);
            *(ushort4*)&dst[32 + 8 * g + 4 * hi] = w1;
        }
    }
}

// ---------------------------------------------------------------------------
extern "C" void kernel_launch(void* const* d_in, const int* in_sizes, int n_in,
                              void* d_out, int out_size, void* d_ws, size_t ws_size,
                              hipStream_t stream)
{
    const float* q  = (const float*)d_in[0];
    const float* k  = (const float*)d_in[1];
    const float* v  = (const float*)d_in[2];
    const float* wq = (const float*)d_in[4];
    const float* bq = (const float*)d_in[5];
    const float* wk = (const float*)d_in[6];
    const float* bk = (const float*)d_in[7];
    const float* wv = (const float*)d_in[8];
    const float* bv = (const float*)d_in[9];
    const float* wo = (const float*)d_in[10];
    const float* fc = (const float*)d_in[11];
    const float* fs = (const float*)d_in[12];
    float* out = (float*)d_out;

    ushort* qB  = (ushort*)d_ws;           // [M][D] bf16
    ushort* kB  = qB  + (size_t)MM * DD;
    ushort* vB  = kB  + (size_t)MM * DD;
    ushort* wqT = vB  + (size_t)MM * DD;   // [n][k] bf16
    ushort* wkT = wqT + (size_t)DD * DD;
    ushort* wvT = wkT + (size_t)DD * DD;
    ushort* woT = wvT + (size_t)DD * DD;
    ushort* Qh  = woT + (size_t)DD * DD;   // [B,H,T,ND] bf16
    ushort* Kh  = Qh  + (size_t)MM * DD;
    ushort* Vh  = Kh  + (size_t)MM * DD;
    ushort* VhT = kB;                      // alias: kB dead after QKV GEMM
    ushort* Op  = qB;                      // alias: qB dead after QKV GEMM

    conv_x3<<<dim3(MM * DD / 4 / 256, 1, 3), 256, 0, stream>>>(q, k, v, qB, kB, vB);
    conv_wT<<<dim3(DD / 64, DD / 64, 4), 256, 0, stream>>>(wq, wk, wv, wo, wqT, wkT, wvT, woT);

    GArgs aq{qB, wqT, bq, (void*)Qh, fc, fs, 2};
    GArgs ak{kB, wkT, bk, (void*)Kh, fc, fs, 1};
    GArgs av{vB, wvT, bv, (void*)Vh, nullptr, nullptr, 0};
    gemm_bf16<0, 128, 64><<<dim3(DD / 64, MM / 128, 3), 256, 0, stream>>>(aq, ak, av);

    transpose_v<<<dim3(TT / 64, BB * HH), 256, 0, stream>>>(Vh, VhT);

    attn_mfma4<<<dim3(NTASK), 512, 0, stream>>>(Qh, Kh, VhT, Op);

    GArgs ao{Op, woT, nullptr, (void*)out, nullptr, nullptr, 0};
    gemm_bf16<1, 64, 64><<<dim3(DD / 64, MM / 64, 1), 256, 0, stream>>>(ao, ao, ao);
}